// Round 1
// baseline (315.729 us; speedup 1.0000x reference)
//
#include <hip/hip_runtime.h>

// ---------- types ----------
using bf16x8 = __attribute__((ext_vector_type(8))) __bf16;
using f32x4  = __attribute__((ext_vector_type(4))) float;

__device__ __forceinline__ short f2bf(float f) {
  unsigned u = __builtin_bit_cast(unsigned, f);
  u += 0x7fffu + ((u >> 16) & 1u);   // RNE
  return (short)(u >> 16);
}

// ---------- fp32 -> bf16 elementwise ----------
__global__ void convert_bf16(const float* __restrict__ in, short* __restrict__ out, int n) {
  int i = (blockIdx.x * blockDim.x + threadIdx.x) * 4;
  if (i + 3 < n) {
    float4 f = *(const float4*)(&in[i]);
    short4 o;
    o.x = f2bf(f.x); o.y = f2bf(f.y); o.z = f2bf(f.z); o.w = f2bf(f.w);
    *(short4*)(&out[i]) = o;
  }
}

// ---------- fp32 [R][C] -> bf16 [C][R] (weights pre-transpose) ----------
__global__ void transpose_bf16(const float* __restrict__ in, short* __restrict__ out,
                               int R, int C) {
  __shared__ short tile[32][33];
  int c0 = blockIdx.x * 32, r0 = blockIdx.y * 32;
  for (int i = threadIdx.y; i < 32; i += 8)
    tile[i][threadIdx.x] = f2bf(in[(r0 + i) * C + c0 + threadIdx.x]);
  __syncthreads();
  for (int i = threadIdx.y; i < 32; i += 8)
    out[(c0 + i) * (long)R + r0 + threadIdx.x] = tile[threadIdx.x][i];
}

// ---------- bf16 MFMA GEMM: C[M][N] = A[M][K] * Bt[N][K]^T ----------
// 128x128 tile, BK=32, 4 waves (2x2) each 64x64. M,N multiples of 128; K mult of 32.
template <bool OUT_BF16>
__global__ __launch_bounds__(256) void gemm_bt(const short* __restrict__ A,
                                               const short* __restrict__ Bt,
                                               void* __restrict__ Cout,
                                               int N, int K) {
  __shared__ short sA[128 * 40];   // pad stride 40 elems (80B)
  __shared__ short sB[128 * 40];
  const int tid  = threadIdx.x;
  const int bm   = blockIdx.y * 128, bn = blockIdx.x * 128;
  const int wave = tid >> 6, lane = tid & 63;
  const int wm = (wave >> 1) * 64, wn = (wave & 1) * 64;
  const int qd = lane >> 4, c16 = lane & 15;

  f32x4 acc[4][4] = {};

  for (int k0 = 0; k0 < K; k0 += 32) {
    __syncthreads();
#pragma unroll
    for (int i = 0; i < 2; i++) {
      int idx = tid + i * 256;          // 0..511
      int row = idx >> 2, seg = idx & 3;
      *(int4*)(&sA[row * 40 + seg * 8]) = *(const int4*)(&A[(bm + row) * (long)K + k0 + seg * 8]);
      *(int4*)(&sB[row * 40 + seg * 8]) = *(const int4*)(&Bt[(bn + row) * (long)K + k0 + seg * 8]);
    }
    __syncthreads();
    bf16x8 af[4], bfr[4];
#pragma unroll
    for (int t = 0; t < 4; t++) {
      af[t]  = *(const bf16x8*)(&sA[(wm + t * 16 + c16) * 40 + qd * 8]);
      bfr[t] = *(const bf16x8*)(&sB[(wn + t * 16 + c16) * 40 + qd * 8]);
    }
#pragma unroll
    for (int mt = 0; mt < 4; mt++)
#pragma unroll
      for (int nt = 0; nt < 4; nt++)
        acc[mt][nt] = __builtin_amdgcn_mfma_f32_16x16x32_bf16(af[mt], bfr[nt], acc[mt][nt], 0, 0, 0);
  }

  // epilogue: C/D layout col=lane&15, row=(lane>>4)*4+reg  [m89-verified]
#pragma unroll
  for (int mt = 0; mt < 4; mt++)
#pragma unroll
    for (int nt = 0; nt < 4; nt++)
#pragma unroll
      for (int r = 0; r < 4; r++) {
        long row = bm + wm + mt * 16 + qd * 4 + r;
        long col = bn + wn + nt * 16 + c16;
        float v = acc[mt][nt][r];
        if constexpr (OUT_BF16) ((short*)Cout)[row * N + col] = f2bf(v);
        else                    ((float*)Cout)[row * N + col] = v;
      }
}

// ---------- flash attention (bf16 MFMA, online softmax) ----------
// grid: (qt=T/64, h=16, b=2); block 256 = 4 waves, wave w handles q rows w*16..w*16+15.
#define CSOFT 0.18033688f   // (1/sqrt(64)) * log2(e)

__global__ __launch_bounds__(256) void attn_kernel(const short* __restrict__ QKV,
                                                   short* __restrict__ Aout) {
  const int qt = blockIdx.x, h = blockIdx.y, b = blockIdx.z;
  const int kvh = h >> 2;
  const int tid = threadIdx.x;
  const int w = tid >> 6, lane = tid & 63;
  const int qd = lane >> 4, c16 = lane & 15;

  __shared__ short sK[64 * 72];        // [j][d], pad stride 72
  __shared__ short sVt[64 * 72];       // [d][j]
  __shared__ short sP[4][16 * 72];     // per-wave P [qrow16][j]

  // Q fragments (A-layout: A[m=lane&15][k=(lane>>4)*8+j]) straight from global
  const long tokQ = (long)b * 2048 + qt * 64 + w * 16 + c16;
  bf16x8 qf[2];
#pragma unroll
  for (int ks = 0; ks < 2; ks++)
    qf[ks] = *(const bf16x8*)(&QKV[tokQ * 1536 + h * 64 + ks * 32 + qd * 8]);

  f32x4 O[4] = {};
  float m_i[4], l_i[4];
#pragma unroll
  for (int r = 0; r < 4; r++) { m_i[r] = -1e30f; l_i[r] = 0.f; }

  const int nkt = qt + 1;
  for (int kt = 0; kt < nkt; kt++) {
    __syncthreads();
    // stage K natural, V transposed
#pragma unroll
    for (int i = 0; i < 2; i++) {
      int idx = tid + i * 256;          // 0..511
      int row = idx >> 3, seg = idx & 7;
      long tok = (long)b * 2048 + kt * 64 + row;
      *(int4*)(&sK[row * 72 + seg * 8]) =
          *(const int4*)(&QKV[tok * 1536 + 1024 + kvh * 64 + seg * 8]);
      union { int4 v; short s[8]; } u;
      u.v = *(const int4*)(&QKV[tok * 1536 + 1280 + kvh * 64 + seg * 8]);
#pragma unroll
      for (int e = 0; e < 8; e++)
        sVt[(seg * 8 + e) * 72 + row] = u.s[e];
    }
    __syncthreads();

    // S = Q K^T  (B-frag: B[k=d][n=j] = K[j][d], row j in lane&15, d contiguous)
    f32x4 S[4];
#pragma unroll
    for (int jt = 0; jt < 4; jt++) {
      bf16x8 kf0 = *(const bf16x8*)(&sK[(jt * 16 + c16) * 72 + 0 + qd * 8]);
      bf16x8 kf1 = *(const bf16x8*)(&sK[(jt * 16 + c16) * 72 + 32 + qd * 8]);
      f32x4 s = {};
      s = __builtin_amdgcn_mfma_f32_16x16x32_bf16(qf[0], kf0, s, 0, 0, 0);
      s = __builtin_amdgcn_mfma_f32_16x16x32_bf16(qf[1], kf1, s, 0, 0, 0);
      S[jt] = s;
    }

    // causal mask (C layout: row=(lane>>4)*4+r, col=jt*16+(lane&15))
    float tmax[4] = {-1e38f, -1e38f, -1e38f, -1e38f};
#pragma unroll
    for (int jt = 0; jt < 4; jt++) {
      int jg = kt * 64 + jt * 16 + c16;
#pragma unroll
      for (int r = 0; r < 4; r++) {
        int qg = qt * 64 + w * 16 + qd * 4 + r;
        if (jg > qg) S[jt][r] = -1e38f;
        tmax[r] = fmaxf(tmax[r], S[jt][r]);
      }
    }

    // online softmax per row; row group = 16 consecutive lanes (same qd)
#pragma unroll
    for (int r = 0; r < 4; r++) {
      float t = tmax[r];
#pragma unroll
      for (int mm = 8; mm >= 1; mm >>= 1)
        t = fmaxf(t, __shfl_xor(t, mm, 64));
      float mnew  = fmaxf(m_i[r], t);
      float alpha = exp2f(CSOFT * (m_i[r] - mnew));
      m_i[r] = mnew;
      l_i[r] *= alpha;
#pragma unroll
      for (int dt = 0; dt < 4; dt++) O[dt][r] *= alpha;
      float rs = 0.f;
#pragma unroll
      for (int jt = 0; jt < 4; jt++) {
        float p = exp2f(CSOFT * (S[jt][r] - mnew));
        rs += p;
        sP[w][(qd * 4 + r) * 72 + jt * 16 + c16] = f2bf(p);
      }
#pragma unroll
      for (int mm = 8; mm >= 1; mm >>= 1)
        rs += __shfl_xor(rs, mm, 64);
      l_i[r] += rs;
    }
    __syncthreads();   // cheap insurance: P writes visible before A-frag reads

    // O += P V   (A=P from per-wave LDS, B[k=j][n=d]=V[j][d]=Vt[d][j])
#pragma unroll
    for (int ks = 0; ks < 2; ks++) {
      bf16x8 pf = *(const bf16x8*)(&sP[w][c16 * 72 + ks * 32 + qd * 8]);
#pragma unroll
      for (int dt = 0; dt < 4; dt++) {
        bf16x8 vf = *(const bf16x8*)(&sVt[(dt * 16 + c16) * 72 + ks * 32 + qd * 8]);
        O[dt] = __builtin_amdgcn_mfma_f32_16x16x32_bf16(pf, vf, O[dt], 0, 0, 0);
      }
    }
  }

  // epilogue: divide by l, store bf16 to attn_out[tok][h*64+d]
#pragma unroll
  for (int r = 0; r < 4; r++) {
    float inv = 1.f / l_i[r];
    long tok = (long)b * 2048 + qt * 64 + w * 16 + qd * 4 + r;
#pragma unroll
    for (int dt = 0; dt < 4; dt++)
      Aout[tok * 1024 + h * 64 + dt * 16 + c16] = f2bf(O[dt][r] * inv);
  }
}

// ---------- launch ----------
extern "C" void kernel_launch(void* const* d_in, const int* in_sizes, int n_in,
                              void* d_out, int out_size, void* d_ws, size_t ws_size,
                              hipStream_t stream) {
  const float* x   = (const float*)d_in[0];   // [2,2048,1024]
  const float* Wq  = (const float*)d_in[1];   // [1024,1024]
  const float* Wkv = (const float*)d_in[2];   // [1024,512]
  const float* Wo  = (const float*)d_in[3];   // [1024,1024]

  char* ws = (char*)d_ws;
  short* xb    = (short*)(ws);                          //  8,388,608 B
  short* Wqkvt = (short*)(ws + 8388608);                //  3,145,728 B  [1536][1024]
  short* Wot   = (short*)(ws + 8388608 + 3145728);      //  2,097,152 B  [1024][1024]
  short* QKV   = (short*)(ws + 13631488);               // 12,582,912 B  [4096][1536]
  short* attn  = (short*)(ws + 26214400);               //  8,388,608 B  [4096][1024]

  convert_bf16<<<4096, 256, 0, stream>>>(x, xb, 4194304);
  transpose_bf16<<<dim3(32, 32), dim3(32, 8), 0, stream>>>(Wq, Wqkvt, 1024, 1024);
  transpose_bf16<<<dim3(16, 32), dim3(32, 8), 0, stream>>>(Wkv, Wqkvt + 1024 * 1024, 1024, 512);
  transpose_bf16<<<dim3(32, 32), dim3(32, 8), 0, stream>>>(Wo, Wot, 1024, 1024);

  // QKV = xb @ Wqkv   (M=4096, N=1536, K=1024), bf16 out
  gemm_bt<true><<<dim3(12, 32), 256, 0, stream>>>(xb, Wqkvt, QKV, 1536, 1024);
  // attention
  attn_kernel<<<dim3(32, 16, 2), 256, 0, stream>>>(QKV, attn);
  // out = attn @ Wo   (M=4096, N=1024, K=1024), fp32 out
  gemm_bt<false><<<dim3(8, 32), 256, 0, stream>>>(attn, Wot, d_out, 1024, 1024);
}

// Round 2
// 238.646 us; speedup vs baseline: 1.3230x; 1.3230x over previous
//
#include <hip/hip_runtime.h>

// ---------- types ----------
using bf16x8 = __attribute__((ext_vector_type(8))) __bf16;
using f32x4  = __attribute__((ext_vector_type(4))) float;

__device__ __forceinline__ short f2bf(float f) {
  unsigned u = __builtin_bit_cast(unsigned, f);
  u += 0x7fffu + ((u >> 16) & 1u);   // RNE
  return (short)(u >> 16);
}

// async global->LDS, 16B per lane; lds base must be wave-uniform
__device__ __forceinline__ void gll16(const void* g, void* l) {
  __builtin_amdgcn_global_load_lds((const __attribute__((address_space(1))) unsigned*)g,
                                   (__attribute__((address_space(3))) unsigned*)l, 16, 0, 0);
}

// ---------- fp32 -> bf16 elementwise ----------
__global__ void convert_bf16(const float* __restrict__ in, short* __restrict__ out, int n) {
  int i = (blockIdx.x * blockDim.x + threadIdx.x) * 4;
  if (i + 3 < n) {
    float4 f = *(const float4*)(&in[i]);
    short4 o;
    o.x = f2bf(f.x); o.y = f2bf(f.y); o.z = f2bf(f.z); o.w = f2bf(f.w);
    *(short4*)(&out[i]) = o;
  }
}

// ---------- fp32 [R][C] -> bf16 [C][R] (weights pre-transpose) ----------
__global__ void transpose_bf16(const float* __restrict__ in, short* __restrict__ out,
                               int R, int C) {
  __shared__ short tile[32][33];
  int c0 = blockIdx.x * 32, r0 = blockIdx.y * 32;
  for (int i = threadIdx.y; i < 32; i += 8)
    tile[i][threadIdx.x] = f2bf(in[(r0 + i) * C + c0 + threadIdx.x]);
  __syncthreads();
  for (int i = threadIdx.y; i < 32; i += 8)
    out[(c0 + i) * (long)R + r0 + threadIdx.x] = tile[threadIdx.x][i];
}

// ---------- bf16 V section of QKV -> Vt[b][kvh][d][t] ----------
__global__ void transpose_v(const short* __restrict__ QKV, short* __restrict__ Vt) {
  __shared__ short tile[32][33];
  int tt = blockIdx.x, dt = blockIdx.y, bkv = blockIdx.z;
  int b = bkv >> 2, kvh = bkv & 3;
  int t0 = tt * 32, d0 = dt * 32;
  for (int i = threadIdx.y; i < 32; i += 8)
    tile[i][threadIdx.x] = QKV[((long)(b * 2048 + t0 + i)) * 1536 + 1280 + kvh * 64 + d0 + threadIdx.x];
  __syncthreads();
  for (int i = threadIdx.y; i < 32; i += 8)
    Vt[((long)(bkv * 64 + d0 + i)) * 2048 + t0 + threadIdx.x] = tile[threadIdx.x][i];
}

// ---------- bf16 MFMA GEMM: C[M][N] = A[M][K] * Bt[N][K]^T ----------
// 128x128 tile, BK=32, global_load_lds staging (m97 pattern), 4 waves 64x64.
template <bool OUT_BF16>
__global__ __launch_bounds__(256) void gemm_bt(const short* __restrict__ A,
                                               const short* __restrict__ Bt,
                                               void* __restrict__ Cout,
                                               int N, int K) {
  __shared__ __attribute__((aligned(16))) short sA[128 * 32];
  __shared__ __attribute__((aligned(16))) short sB[128 * 32];
  const int tid  = threadIdx.x;
  const int bm   = blockIdx.y * 128, bn = blockIdx.x * 128;
  const int wave = tid >> 6, lane = tid & 63;
  const int wm = (wave >> 1) * 64, wn = (wave & 1) * 64;
  const int qd = lane >> 4, c16 = lane & 15;

  f32x4 acc[4][4] = {};

  for (int k0 = 0; k0 < K; k0 += 32) {
    __syncthreads();
#pragma unroll
    for (int i = 0; i < 2; i++) {
      int c = i * 256 + tid;            // chunk 0..511
      int row = c >> 2, cc = c & 3;
      gll16(&A[(bm + row) * (long)K + k0 + cc * 8], &sA[(i * 256 + wave * 64) * 8]);
      gll16(&Bt[(bn + row) * (long)K + k0 + cc * 8], &sB[(i * 256 + wave * 64) * 8]);
    }
    __syncthreads();
    bf16x8 af[4], bfr[4];
#pragma unroll
    for (int t = 0; t < 4; t++) {
      af[t]  = *(const bf16x8*)(&sA[(wm + t * 16 + c16) * 32 + qd * 8]);
      bfr[t] = *(const bf16x8*)(&sB[(wn + t * 16 + c16) * 32 + qd * 8]);
    }
#pragma unroll
    for (int mt = 0; mt < 4; mt++)
#pragma unroll
      for (int nt = 0; nt < 4; nt++)
        acc[mt][nt] = __builtin_amdgcn_mfma_f32_16x16x32_bf16(af[mt], bfr[nt], acc[mt][nt], 0, 0, 0);
  }

  // epilogue: C/D layout col=lane&15, row=(lane>>4)*4+reg  [m89-verified]
#pragma unroll
  for (int mt = 0; mt < 4; mt++)
#pragma unroll
    for (int nt = 0; nt < 4; nt++)
#pragma unroll
      for (int r = 0; r < 4; r++) {
        long row = bm + wm + mt * 16 + qd * 4 + r;
        long col = bn + wn + nt * 16 + c16;
        float v = acc[mt][nt][r];
        if constexpr (OUT_BF16) ((short*)Cout)[row * N + col] = f2bf(v);
        else                    ((float*)Cout)[row * N + col] = v;
      }
}

// ---------- flash attention v2: S^T orientation, per-lane softmax ----------
// grid (16,16,2): qt = 15-bx (long blocks first), h, b. Block 256 = 4 waves.
// Wave w owns q rows q0+w*32 .. +32 (2 strips of 16). Per-lane q = lane&15.
#define CSOFT 0.18033688f   // (1/sqrt(64)) * log2(e)

__global__ __launch_bounds__(256) void attn_kernel(const short* __restrict__ QKV,
                                                   const short* __restrict__ Vt,
                                                   short* __restrict__ Aout) {
  const int qt = 15 - blockIdx.x, h = blockIdx.y, b = blockIdx.z;
  const int kvh = h >> 2, bkv = b * 4 + kvh;
  const int tid = threadIdx.x;
  const int w = tid >> 6, lane = tid & 63;
  const int qd = lane >> 4, c16 = lane & 15;
  const int q0 = qt * 128;

  // swizzled, stride 64 shorts: element (r, cc-octet) at r*64 + (cc ^ (r&7))*8
  __shared__ __attribute__((aligned(16))) short sK[64 * 64];   // [j][d]
  __shared__ __attribute__((aligned(16))) short sVt[64 * 64];  // [d][j]
  __shared__ __attribute__((aligned(16))) short sP[4][32 * 72]; // per wave [q32][j64]

  // Q fragments (B-operand: lane c16 = q, octet over d), from global once
  bf16x8 qf[2][2];
#pragma unroll
  for (int s = 0; s < 2; s++) {
    long tok = (long)b * 2048 + q0 + w * 32 + s * 16 + c16;
#pragma unroll
    for (int ks = 0; ks < 2; ks++)
      qf[s][ks] = *(const bf16x8*)(&QKV[tok * 1536 + h * 64 + ks * 32 + qd * 8]);
  }

  f32x4 Ot[2][4] = {};            // O^T: row=d (qd*4+r within dt*16), col=q=c16
  float m_i[2] = {-1e30f, -1e30f}, l_i[2] = {0.f, 0.f};

  const int ntiles = 2 * qt + 2;
  const int last_w = 2 * qt + (w >> 1);   // waves 0,1: diag at 2qt; waves 2,3: at 2qt+1

  for (int kt = 0; kt < ntiles; kt++) {
    __syncthreads();
    // ---- stage K tile + Vt tile via global_load_lds (16B, swizzled) ----
#pragma unroll
    for (int i = 0; i < 2; i++) {
      int c = i * 256 + tid;            // chunk 0..511
      int r = c >> 3, cc = c & 7;
      gll16(&QKV[((long)(b * 2048 + kt * 64 + r)) * 1536 + 1024 + kvh * 64 + ((cc ^ (r & 7)) * 8)],
            &sK[(i * 256 + w * 64) * 8]);
      gll16(&Vt[((long)(bkv * 64 + r)) * 2048 + kt * 64 + ((cc ^ (r & 7)) * 8)],
            &sVt[(i * 256 + w * 64) * 8]);
    }
    __syncthreads();

    if (kt <= last_w) {
      // ---- S^T = K Q^T : A = K chunk (c16 = j), B = Q (c16 = q) ----
      f32x4 St[2][4];
#pragma unroll
      for (int jc = 0; jc < 4; jc++) {
        bf16x8 kf0 = *(const bf16x8*)(&sK[(jc * 16 + c16) * 64 + ((0 + qd) ^ (c16 & 7)) * 8]);
        bf16x8 kf1 = *(const bf16x8*)(&sK[(jc * 16 + c16) * 64 + ((4 + qd) ^ (c16 & 7)) * 8]);
#pragma unroll
        for (int s = 0; s < 2; s++) {
          f32x4 z = {};
          z = __builtin_amdgcn_mfma_f32_16x16x32_bf16(kf0, qf[s][0], z, 0, 0, 0);
          z = __builtin_amdgcn_mfma_f32_16x16x32_bf16(kf1, qf[s][1], z, 0, 0, 0);
          St[s][jc] = z;
        }
      }

      // ---- causal mask only on this wave's diagonal tile ----
      if (kt == last_w) {
#pragma unroll
        for (int s = 0; s < 2; s++) {
          int qg = q0 + w * 32 + s * 16 + c16;
#pragma unroll
          for (int jc = 0; jc < 4; jc++)
#pragma unroll
            for (int r = 0; r < 4; r++)
              if (kt * 64 + jc * 16 + qd * 4 + r > qg) St[s][jc][r] = -3e38f;
        }
      }

      // ---- online softmax, per-lane (q = c16); reduce over j via 2 shuffles ----
#pragma unroll
      for (int s = 0; s < 2; s++) {
        float t = -3e38f;
#pragma unroll
        for (int jc = 0; jc < 4; jc++)
#pragma unroll
          for (int r = 0; r < 4; r++) t = fmaxf(t, St[s][jc][r]);
        t = fmaxf(t, __shfl_xor(t, 16, 64));
        t = fmaxf(t, __shfl_xor(t, 32, 64));
        float mnew  = fmaxf(m_i[s], t);
        float alpha = exp2f(CSOFT * (m_i[s] - mnew));
        m_i[s] = mnew;
#pragma unroll
        for (int dt = 0; dt < 4; dt++)
#pragma unroll
          for (int r = 0; r < 4; r++) Ot[s][dt][r] *= alpha;
        float rs = 0.f;
#pragma unroll
        for (int jc = 0; jc < 4; jc++) {
          short4 pk;
          float p0 = exp2f(CSOFT * (St[s][jc][0] - mnew));
          float p1 = exp2f(CSOFT * (St[s][jc][1] - mnew));
          float p2 = exp2f(CSOFT * (St[s][jc][2] - mnew));
          float p3 = exp2f(CSOFT * (St[s][jc][3] - mnew));
          rs += (p0 + p1) + (p2 + p3);
          pk.x = f2bf(p0); pk.y = f2bf(p1); pk.z = f2bf(p2); pk.w = f2bf(p3);
          *(short4*)(&sP[w][(s * 16 + c16) * 72 + jc * 16 + qd * 4]) = pk;
        }
        rs += __shfl_xor(rs, 16, 64);
        rs += __shfl_xor(rs, 32, 64);
        l_i[s] = l_i[s] * alpha + rs;
      }
      // ensure per-wave sP writes retired before fragment reads
      asm volatile("s_waitcnt lgkmcnt(0)" ::: "memory");

      // ---- O^T += V^T P^T : A = Vt chunk (c16 = d), B = P^T (c16 = q) ----
#pragma unroll
      for (int ks2 = 0; ks2 < 2; ks2++) {
        bf16x8 pf0 = *(const bf16x8*)(&sP[w][(0 + c16) * 72 + ks2 * 32 + qd * 8]);
        bf16x8 pf1 = *(const bf16x8*)(&sP[w][(16 + c16) * 72 + ks2 * 32 + qd * 8]);
#pragma unroll
        for (int dt = 0; dt < 4; dt++) {
          bf16x8 vf = *(const bf16x8*)(&sVt[(dt * 16 + c16) * 64 + (((ks2 * 4 + qd) ^ (c16 & 7)) * 8)]);
          Ot[0][dt] = __builtin_amdgcn_mfma_f32_16x16x32_bf16(vf, pf0, Ot[0][dt], 0, 0, 0);
          Ot[1][dt] = __builtin_amdgcn_mfma_f32_16x16x32_bf16(vf, pf1, Ot[1][dt], 0, 0, 0);
        }
      }
    }
  }

  // ---- epilogue: per-lane 1/l, store O^T -> attn[tok][h*64+d] (8B packed) ----
#pragma unroll
  for (int s = 0; s < 2; s++) {
    float inv = 1.f / l_i[s];
    long tok = (long)b * 2048 + q0 + w * 32 + s * 16 + c16;
#pragma unroll
    for (int dt = 0; dt < 4; dt++) {
      short4 o;
      o.x = f2bf(Ot[s][dt][0] * inv);
      o.y = f2bf(Ot[s][dt][1] * inv);
      o.z = f2bf(Ot[s][dt][2] * inv);
      o.w = f2bf(Ot[s][dt][3] * inv);
      *(short4*)(&Aout[tok * 1024 + h * 64 + dt * 16 + qd * 4]) = o;
    }
  }
}

// ---------- launch ----------
extern "C" void kernel_launch(void* const* d_in, const int* in_sizes, int n_in,
                              void* d_out, int out_size, void* d_ws, size_t ws_size,
                              hipStream_t stream) {
  const float* x   = (const float*)d_in[0];   // [2,2048,1024]
  const float* Wq  = (const float*)d_in[1];   // [1024,1024]
  const float* Wkv = (const float*)d_in[2];   // [1024,512]
  const float* Wo  = (const float*)d_in[3];   // [1024,1024]

  char* ws = (char*)d_ws;
  short* xb    = (short*)(ws);                          //  8,388,608 B (dead after gemm1)
  short* Wqkvt = (short*)(ws + 8388608);                //  3,145,728 B  [1536][1024]
  short* Wot   = (short*)(ws + 11534336);               //  2,097,152 B  [1024][1024]
  short* QKV   = (short*)(ws + 13631488);               // 12,582,912 B  [4096][1536]
  short* attn  = (short*)(ws + 26214400);               //  8,388,608 B  [4096][1024]
  short* Vtb   = (short*)(ws);                          //  4,194,304 B, aliases xb (safe: xb dead)

  convert_bf16<<<4096, 256, 0, stream>>>(x, xb, 4194304);
  transpose_bf16<<<dim3(32, 32), dim3(32, 8), 0, stream>>>(Wq, Wqkvt, 1024, 1024);
  transpose_bf16<<<dim3(16, 32), dim3(32, 8), 0, stream>>>(Wkv, Wqkvt + 1024 * 1024, 1024, 512);
  transpose_bf16<<<dim3(32, 32), dim3(32, 8), 0, stream>>>(Wo, Wot, 1024, 1024);

  // QKV = xb @ Wqkv   (M=4096, N=1536, K=1024), bf16 out
  gemm_bt<true><<<dim3(12, 32), 256, 0, stream>>>(xb, Wqkvt, QKV, 1536, 1024);
  // V -> Vt[b][kvh][d][t]  (xb no longer needed; Vtb aliases it)
  transpose_v<<<dim3(64, 2, 8), dim3(32, 8), 0, stream>>>(QKV, Vtb);
  // attention (128 q rows/block, S^T orientation)
  attn_kernel<<<dim3(16, 16, 2), 256, 0, stream>>>(QKV, Vtb, attn);
  // out = attn @ Wo   (M=4096, N=1024, K=1024), fp32 out
  gemm_bt<false><<<dim3(8, 32), 256, 0, stream>>>(attn, Wot, d_out, 1024, 1024);
}

// Round 3
// 195.084 us; speedup vs baseline: 1.6184x; 1.2233x over previous
//
#include <hip/hip_runtime.h>

// ---------- types ----------
using bf16x8 = __attribute__((ext_vector_type(8))) __bf16;
using f32x4  = __attribute__((ext_vector_type(4))) float;

__device__ __forceinline__ short f2bf(float f) {
  unsigned u = __builtin_bit_cast(unsigned, f);
  u += 0x7fffu + ((u >> 16) & 1u);   // RNE
  return (short)(u >> 16);
}

// async global->LDS, 16B per lane; lds base must be wave-uniform
__device__ __forceinline__ void gll16(const void* g, void* l) {
  __builtin_amdgcn_global_load_lds((const __attribute__((address_space(1))) unsigned*)g,
                                   (__attribute__((address_space(3))) unsigned*)l, 16, 0, 0);
}

// ---------- fp32 -> bf16 elementwise ----------
__global__ void convert_bf16(const float* __restrict__ in, short* __restrict__ out, int n) {
  int i = (blockIdx.x * blockDim.x + threadIdx.x) * 4;
  if (i + 3 < n) {
    float4 f = *(const float4*)(&in[i]);
    short4 o;
    o.x = f2bf(f.x); o.y = f2bf(f.y); o.z = f2bf(f.z); o.w = f2bf(f.w);
    *(short4*)(&out[i]) = o;
  }
}

// ---------- fp32 [R][C] -> bf16 [C][R] (weights pre-transpose) ----------
__global__ void transpose_bf16(const float* __restrict__ in, short* __restrict__ out,
                               int R, int C) {
  __shared__ short tile[32][33];
  int c0 = blockIdx.x * 32, r0 = blockIdx.y * 32;
  for (int i = threadIdx.y; i < 32; i += 8)
    tile[i][threadIdx.x] = f2bf(in[(r0 + i) * C + c0 + threadIdx.x]);
  __syncthreads();
  for (int i = threadIdx.y; i < 32; i += 8)
    out[(c0 + i) * (long)R + r0 + threadIdx.x] = tile[threadIdx.x][i];
}

// ---------- bf16 V section of QKV -> Vt[b][kvh][d][t] ----------
__global__ void transpose_v(const short* __restrict__ QKV, short* __restrict__ Vt) {
  __shared__ short tile[32][33];
  int tt = blockIdx.x, dt = blockIdx.y, bkv = blockIdx.z;
  int b = bkv >> 2, kvh = bkv & 3;
  int t0 = tt * 32, d0 = dt * 32;
  for (int i = threadIdx.y; i < 32; i += 8)
    tile[i][threadIdx.x] = QKV[((long)(b * 2048 + t0 + i)) * 1536 + 1280 + kvh * 64 + d0 + threadIdx.x];
  __syncthreads();
  for (int i = threadIdx.y; i < 32; i += 8)
    Vt[((long)(bkv * 64 + d0 + i)) * 2048 + t0 + threadIdx.x] = tile[threadIdx.x][i];
}

// ---------- bf16 MFMA GEMM: C[M][N] = A[M][K] * Bt[N][K]^T ----------
// 64x128 tile, BK=32, gll16 staging; 4 waves in 2x2, each 32x64. 
// Chosen over 128x128 for occupancy (3 blocks/CU at grid 768) on short-K shapes.
template <bool OUT_BF16>
__global__ __launch_bounds__(256) void gemm_bt(const short* __restrict__ A,
                                               const short* __restrict__ Bt,
                                               void* __restrict__ Cout,
                                               int N, int K) {
  __shared__ __attribute__((aligned(16))) short sA[64 * 32];
  __shared__ __attribute__((aligned(16))) short sB[128 * 32];
  const int tid  = threadIdx.x;
  const int bm   = blockIdx.y * 64, bn = blockIdx.x * 128;
  const int wave = tid >> 6, lane = tid & 63;
  const int wm = (wave >> 1) * 32, wn = (wave & 1) * 64;
  const int qd = lane >> 4, c16 = lane & 15;

  f32x4 acc[2][4] = {};

  for (int k0 = 0; k0 < K; k0 += 32) {
    __syncthreads();
    {
      int row = tid >> 2, cc = tid & 3;
      gll16(&A[(bm + row) * (long)K + k0 + cc * 8], &sA[(wave * 64) * 8]);
    }
#pragma unroll
    for (int i = 0; i < 2; i++) {
      int c = i * 256 + tid;
      int row = c >> 2, cc = c & 3;
      gll16(&Bt[(bn + row) * (long)K + k0 + cc * 8], &sB[(i * 256 + wave * 64) * 8]);
    }
    __syncthreads();
    bf16x8 af[2], bfr[4];
#pragma unroll
    for (int t = 0; t < 2; t++)
      af[t]  = *(const bf16x8*)(&sA[(wm + t * 16 + c16) * 32 + qd * 8]);
#pragma unroll
    for (int t = 0; t < 4; t++)
      bfr[t] = *(const bf16x8*)(&sB[(wn + t * 16 + c16) * 32 + qd * 8]);
#pragma unroll
    for (int mt = 0; mt < 2; mt++)
#pragma unroll
      for (int nt = 0; nt < 4; nt++)
        acc[mt][nt] = __builtin_amdgcn_mfma_f32_16x16x32_bf16(af[mt], bfr[nt], acc[mt][nt], 0, 0, 0);
  }

  // epilogue: C/D layout col=lane&15, row=(lane>>4)*4+reg  [m89-verified]
#pragma unroll
  for (int mt = 0; mt < 2; mt++)
#pragma unroll
    for (int nt = 0; nt < 4; nt++)
#pragma unroll
      for (int r = 0; r < 4; r++) {
        long row = bm + wm + mt * 16 + qd * 4 + r;
        long col = bn + wn + nt * 16 + c16;
        float v = acc[mt][nt][r];
        if constexpr (OUT_BF16) ((short*)Cout)[row * N + col] = f2bf(v);
        else                    ((float*)Cout)[row * N + col] = v;
      }
}

// ---------- flash attention v3: GQA-shared K/V, static-max softmax ----------
// Flat grid 512: qt = 63-(bx>>3) descending (long blocks first), kvh=(bx>>1)&3, b=bx&1.
// Block = 4 waves = the 4 Q-heads sharing kv-head kvh. Each wave: 32 q rows
// (2 strips of 16), q0 = qt*32. S^T orientation: per-lane q = lane&15.
#define CSOFT 0.18033688f            // (1/sqrt(64)) * log2(e)
#define CMAX  (CSOFT * 12.0f)        // static max (raw-score units); softmax is
                                     // invariant to the shift, exp2 can't overflow
__global__ __launch_bounds__(256) void attn_kernel(const short* __restrict__ QKV,
                                                   const short* __restrict__ Vt,
                                                   short* __restrict__ Aout) {
  const int bx = blockIdx.x;
  const int qt = 63 - (bx >> 3);
  const int kvh = (bx >> 1) & 3, b = bx & 1;
  const int bkv = b * 4 + kvh;
  const int tid = threadIdx.x;
  const int w = tid >> 6, lane = tid & 63;
  const int qd = lane >> 4, c16 = lane & 15;
  const int h = kvh * 4 + w;
  const int q0 = qt * 32;

  // swizzled, stride 64 shorts: row r octet o stored at r*64 + (o ^ (r&7))*8
  __shared__ __attribute__((aligned(16))) short sK[64 * 64];    // [j][d]
  __shared__ __attribute__((aligned(16))) short sVt[64 * 64];   // [d][j]
  __shared__ __attribute__((aligned(16))) short sP[4][32 * 72]; // per wave [q32][j64]

  // Q fragments (B-operand: lane c16 = q, octet over d), from global once
  bf16x8 qf[2][2];
#pragma unroll
  for (int s = 0; s < 2; s++) {
    long tok = (long)b * 2048 + q0 + s * 16 + c16;
#pragma unroll
    for (int ks = 0; ks < 2; ks++)
      qf[s][ks] = *(const bf16x8*)(&QKV[tok * 1536 + h * 64 + ks * 32 + qd * 8]);
  }

  f32x4 Ot[2][4] = {};              // O^T: row=d, col=q=c16 (un-normalized)
  float l_i[2] = {0.f, 0.f};        // per-lane partial sum over this lane's j's

  const int ntiles = (qt >> 1) + 1;
  for (int kt = 0; kt < ntiles; kt++) {
    __syncthreads();
    // ---- stage K tile + Vt tile via gll16 (16B, xor-swizzled source octet) ----
#pragma unroll
    for (int i = 0; i < 2; i++) {
      int c = i * 256 + tid;
      int r = c >> 3, cc = c & 7;
      gll16(&QKV[((long)(b * 2048 + kt * 64 + r)) * 1536 + 1024 + kvh * 64 + ((cc ^ (r & 7)) * 8)],
            &sK[(i * 256 + w * 64) * 8]);
      gll16(&Vt[((long)(bkv * 64 + r)) * 2048 + kt * 64 + ((cc ^ (r & 7)) * 8)],
            &sVt[(i * 256 + w * 64) * 8]);
    }
    __syncthreads();

    // ---- S^T = K Q^T : A = K (c16 = j), B = Q (c16 = q); kf shared by strips ----
    f32x4 St[2][4];
#pragma unroll
    for (int jc = 0; jc < 4; jc++) {
      int rr = jc * 16 + c16;
      bf16x8 kf0 = *(const bf16x8*)(&sK[rr * 64 + ((0 + qd) ^ (c16 & 7)) * 8]);
      bf16x8 kf1 = *(const bf16x8*)(&sK[rr * 64 + ((4 + qd) ^ (c16 & 7)) * 8]);
#pragma unroll
      for (int s = 0; s < 2; s++) {
        f32x4 z = {};
        z = __builtin_amdgcn_mfma_f32_16x16x32_bf16(kf0, qf[s][0], z, 0, 0, 0);
        z = __builtin_amdgcn_mfma_f32_16x16x32_bf16(kf1, qf[s][1], z, 0, 0, 0);
        St[s][jc] = z;
      }
    }

    // ---- causal mask on the diagonal (last) tile only ----
    if (kt == ntiles - 1) {
#pragma unroll
      for (int s = 0; s < 2; s++) {
        int qg = q0 + s * 16 + c16 - kt * 64;   // q rel. to tile
#pragma unroll
        for (int jc = 0; jc < 4; jc++)
#pragma unroll
          for (int r = 0; r < 4; r++)
            if (jc * 16 + qd * 4 + r > qg) St[s][jc][r] = -3e38f;
      }
    }

    // ---- static-max softmax: p = exp2(CSOFT*s - CMAX); no shuffles, no rescale ----
#pragma unroll
    for (int s = 0; s < 2; s++) {
      float rs = 0.f;
#pragma unroll
      for (int jc = 0; jc < 4; jc++) {
        unsigned u[4];
#pragma unroll
        for (int r = 0; r < 4; r++) {
          float p = exp2f(fmaf(CSOFT, St[s][jc][r], -CMAX));
          u[r] = __builtin_bit_cast(unsigned, p) & 0xffff0000u;   // truncate to bf16
          rs += __builtin_bit_cast(float, u[r]);                  // l from truncated p
        }
        int2 pk;
        pk.x = (int)((u[0] >> 16) | u[1]);
        pk.y = (int)((u[2] >> 16) | u[3]);
        *(int2*)(&sP[w][(s * 16 + c16) * 72 + jc * 16 + qd * 4]) = pk;
      }
      l_i[s] += rs;
    }
    asm volatile("s_waitcnt lgkmcnt(0)" ::: "memory");  // own-wave sP writes retired

    // ---- O^T += V^T P^T : A = Vt (c16 = d), B = P^T (c16 = q); vf shared ----
#pragma unroll
    for (int ks2 = 0; ks2 < 2; ks2++) {
      bf16x8 pf0 = *(const bf16x8*)(&sP[w][(0 + c16) * 72 + ks2 * 32 + qd * 8]);
      bf16x8 pf1 = *(const bf16x8*)(&sP[w][(16 + c16) * 72 + ks2 * 32 + qd * 8]);
#pragma unroll
      for (int dt = 0; dt < 4; dt++) {
        bf16x8 vf = *(const bf16x8*)(&sVt[(dt * 16 + c16) * 64 + (((ks2 * 4 + qd) ^ (c16 & 7)) * 8)]);
        Ot[0][dt] = __builtin_amdgcn_mfma_f32_16x16x32_bf16(vf, pf0, Ot[0][dt], 0, 0, 0);
        Ot[1][dt] = __builtin_amdgcn_mfma_f32_16x16x32_bf16(vf, pf1, Ot[1][dt], 0, 0, 0);
      }
    }
  }

  // ---- epilogue: reduce l across the 4 qd groups, normalize, store O^T ----
#pragma unroll
  for (int s = 0; s < 2; s++) {
    float l = l_i[s];
    l += __shfl_xor(l, 16, 64);
    l += __shfl_xor(l, 32, 64);
    float inv = 1.f / l;
    long tok = (long)b * 2048 + q0 + s * 16 + c16;
#pragma unroll
    for (int dt = 0; dt < 4; dt++) {
      short4 o;
      o.x = f2bf(Ot[s][dt][0] * inv);
      o.y = f2bf(Ot[s][dt][1] * inv);
      o.z = f2bf(Ot[s][dt][2] * inv);
      o.w = f2bf(Ot[s][dt][3] * inv);
      *(short4*)(&Aout[tok * 1024 + h * 64 + dt * 16 + qd * 4]) = o;
    }
  }
}

// ---------- launch ----------
extern "C" void kernel_launch(void* const* d_in, const int* in_sizes, int n_in,
                              void* d_out, int out_size, void* d_ws, size_t ws_size,
                              hipStream_t stream) {
  const float* x   = (const float*)d_in[0];   // [2,2048,1024]
  const float* Wq  = (const float*)d_in[1];   // [1024,1024]
  const float* Wkv = (const float*)d_in[2];   // [1024,512]
  const float* Wo  = (const float*)d_in[3];   // [1024,1024]

  char* ws = (char*)d_ws;
  short* xb    = (short*)(ws);                          //  8,388,608 B (dead after gemm1)
  short* Wqkvt = (short*)(ws + 8388608);                //  3,145,728 B  [1536][1024]
  short* Wot   = (short*)(ws + 11534336);               //  2,097,152 B  [1024][1024]
  short* QKV   = (short*)(ws + 13631488);               // 12,582,912 B  [4096][1536]
  short* attn  = (short*)(ws + 26214400);               //  8,388,608 B  [4096][1024]
  short* Vtb   = (short*)(ws);                          //  4,194,304 B, aliases xb (safe: xb dead)

  convert_bf16<<<4096, 256, 0, stream>>>(x, xb, 4194304);
  transpose_bf16<<<dim3(32, 32), dim3(32, 8), 0, stream>>>(Wq, Wqkvt, 1024, 1024);
  transpose_bf16<<<dim3(16, 32), dim3(32, 8), 0, stream>>>(Wkv, Wqkvt + 1024 * 1024, 1024, 512);
  transpose_bf16<<<dim3(32, 32), dim3(32, 8), 0, stream>>>(Wo, Wot, 1024, 1024);

  // QKV = xb @ Wqkv   (M=4096, N=1536, K=1024), bf16 out; grid 768 = 3 blocks/CU
  gemm_bt<true><<<dim3(12, 64), 256, 0, stream>>>(xb, Wqkvt, QKV, 1536, 1024);
  // V -> Vt[b][kvh][d][t]  (xb no longer needed; Vtb aliases it)
  transpose_v<<<dim3(64, 2, 8), dim3(32, 8), 0, stream>>>(QKV, Vtb);
  // attention: 512 blocks, qt descending, 4 heads of one kv-group per block
  attn_kernel<<<dim3(512), 256, 0, stream>>>(QKV, Vtb, attn);
  // out = attn @ Wo   (M=4096, N=1024, K=1024), fp32 out; grid 512 = 2 blocks/CU
  gemm_bt<false><<<dim3(8, 64), 256, 0, stream>>>(attn, Wot, d_out, 1024, 1024);
}

// Round 4
// 190.294 us; speedup vs baseline: 1.6592x; 1.0252x over previous
//
#include <hip/hip_runtime.h>

// ---------- types ----------
using bf16x8 = __attribute__((ext_vector_type(8))) __bf16;
using f32x4  = __attribute__((ext_vector_type(4))) float;

__device__ __forceinline__ short f2bf(float f) {
  unsigned u = __builtin_bit_cast(unsigned, f);
  u += 0x7fffu + ((u >> 16) & 1u);   // RNE
  return (short)(u >> 16);
}

// async global->LDS, 16B per lane; lds base must be wave-uniform
__device__ __forceinline__ void gll16(const void* g, void* l) {
  __builtin_amdgcn_global_load_lds((const __attribute__((address_space(1))) unsigned*)g,
                                   (__attribute__((address_space(3))) unsigned*)l, 16, 0, 0);
}

// ---------- fp32 -> bf16 elementwise ----------
__global__ void convert_bf16(const float* __restrict__ in, short* __restrict__ out, int n) {
  int i = (blockIdx.x * blockDim.x + threadIdx.x) * 4;
  if (i + 3 < n) {
    float4 f = *(const float4*)(&in[i]);
    short4 o;
    o.x = f2bf(f.x); o.y = f2bf(f.y); o.z = f2bf(f.z); o.w = f2bf(f.w);
    *(short4*)(&out[i]) = o;
  }
}

// ---------- all three weight transposes in one launch ----------
// fp32 [1024][C] -> bf16 [C][1024]; z selects {Wq, Wkv, Wo}
__global__ void prep_weights(const float* __restrict__ Wq, const float* __restrict__ Wkv,
                             const float* __restrict__ Wo,
                             short* __restrict__ Wqkvt, short* __restrict__ Wot) {
  __shared__ short tile[32][33];
  const int z = blockIdx.z;
  const float* src; short* dst; int C;
  if (z == 0)      { src = Wq;  dst = Wqkvt;               C = 1024; }
  else if (z == 1) { if (blockIdx.x >= 16) return;
                     src = Wkv; dst = Wqkvt + 1024 * 1024; C = 512;  }
  else             { src = Wo;  dst = Wot;                 C = 1024; }
  int c0 = blockIdx.x * 32, r0 = blockIdx.y * 32;
  for (int i = threadIdx.y; i < 32; i += 8)
    tile[i][threadIdx.x] = f2bf(src[(r0 + i) * C + c0 + threadIdx.x]);
  __syncthreads();
  for (int i = threadIdx.y; i < 32; i += 8)
    dst[(c0 + i) * 1024L + r0 + threadIdx.x] = tile[threadIdx.x][i];
}

// ---------- bf16 V section of QKV -> Vt[b][kvh][d][t] ----------
__global__ void transpose_v(const short* __restrict__ QKV, short* __restrict__ Vt) {
  __shared__ short tile[32][33];
  int tt = blockIdx.x, dt = blockIdx.y, bkv = blockIdx.z;
  int b = bkv >> 2, kvh = bkv & 3;
  int t0 = tt * 32, d0 = dt * 32;
  for (int i = threadIdx.y; i < 32; i += 8)
    tile[i][threadIdx.x] = QKV[((long)(b * 2048 + t0 + i)) * 1536 + 1280 + kvh * 64 + d0 + threadIdx.x];
  __syncthreads();
  for (int i = threadIdx.y; i < 32; i += 8)
    Vt[((long)(bkv * 64 + d0 + i)) * 2048 + t0 + threadIdx.x] = tile[threadIdx.x][i];
}

// ---------- bf16 MFMA GEMM: C[M][N] = A[M][K] * Bt[N][K]^T ----------
// 64x128 tile, BK=32, DOUBLE-BUFFERED gll16 staging with raw s_barrier +
// fine vmcnt (prefetch next K-slice while computing current).
template <bool OUT_BF16>
__global__ __launch_bounds__(256) void gemm_bt(const short* __restrict__ A,
                                               const short* __restrict__ Bt,
                                               void* __restrict__ Cout,
                                               int N, int K) {
  __shared__ __attribute__((aligned(16))) short sA[2][64 * 32];
  __shared__ __attribute__((aligned(16))) short sB[2][128 * 32];
  const int tid  = threadIdx.x;
  const int bm   = blockIdx.y * 64, bn = blockIdx.x * 128;
  const int wave = tid >> 6, lane = tid & 63;
  const int wm = (wave >> 1) * 32, wn = (wave & 1) * 64;
  const int qd = lane >> 4, c16 = lane & 15;

  f32x4 acc[2][4] = {};

  auto stage = [&](int it, int d) {
    int k0 = it * 32;
    {
      int row = tid >> 2, cc = tid & 3;
      gll16(&A[(bm + row) * (long)K + k0 + cc * 8], &sA[d][(wave * 64) * 8]);
    }
#pragma unroll
    for (int i = 0; i < 2; i++) {
      int c = i * 256 + tid;
      int row = c >> 2, cc = c & 3;
      gll16(&Bt[(bn + row) * (long)K + k0 + cc * 8], &sB[d][(i * 256 + wave * 64) * 8]);
    }
  };

  const int niter = K >> 5;
  stage(0, 0);
  for (int it = 0; it < niter; it++) {
    const int cur = it & 1;
    asm volatile("" ::: "memory");
    __builtin_amdgcn_s_barrier();            // buf[cur^1] free (it-1 compute done)
    if (it + 1 < niter) {
      stage(it + 1, cur ^ 1);                // 3 gll16/thread
      asm volatile("s_waitcnt vmcnt(3)" ::: "memory");   // cur's stage retired
    } else {
      asm volatile("s_waitcnt vmcnt(0)" ::: "memory");
    }
    __builtin_amdgcn_s_barrier();            // all waves' cur data visible
    asm volatile("" ::: "memory");

    bf16x8 af[2], bfr[4];
#pragma unroll
    for (int t = 0; t < 2; t++)
      af[t]  = *(const bf16x8*)(&sA[cur][(wm + t * 16 + c16) * 32 + qd * 8]);
#pragma unroll
    for (int t = 0; t < 4; t++)
      bfr[t] = *(const bf16x8*)(&sB[cur][(wn + t * 16 + c16) * 32 + qd * 8]);
#pragma unroll
    for (int mt = 0; mt < 2; mt++)
#pragma unroll
      for (int nt = 0; nt < 4; nt++)
        acc[mt][nt] = __builtin_amdgcn_mfma_f32_16x16x32_bf16(af[mt], bfr[nt], acc[mt][nt], 0, 0, 0);
  }

  // epilogue: C/D layout col=lane&15, row=(lane>>4)*4+reg  [m89-verified]
#pragma unroll
  for (int mt = 0; mt < 2; mt++)
#pragma unroll
    for (int nt = 0; nt < 4; nt++)
#pragma unroll
      for (int r = 0; r < 4; r++) {
        long row = bm + wm + mt * 16 + qd * 4 + r;
        long col = bn + wn + nt * 16 + c16;
        float v = acc[mt][nt][r];
        if constexpr (OUT_BF16) ((short*)Cout)[row * N + col] = f2bf(v);
        else                    ((float*)Cout)[row * N + col] = v;
      }
}

// ---------- flash attention v4: dbuf K/V prefetch, balanced grid ----------
// Flat grid 512. First 256 blocks: qt = 63-(bx>>3) (long, desc); second 256:
// qt = (bx>>3)-32 (short, asc) -> CU pair sums ~constant tiles (makespan).
// Block = 4 waves = 4 Q-heads of kv-group kvh; wave: 32 q rows, q0=qt*32.
// S^T orientation: per-lane q = lane&15.
#define CSOFT 0.18033688f            // (1/sqrt(64)) * log2(e)
#define CMAX  (CSOFT * 12.0f)        // static max shift; softmax shift-invariant

__global__ __launch_bounds__(256) void attn_kernel(const short* __restrict__ QKV,
                                                   const short* __restrict__ Vt,
                                                   short* __restrict__ Aout) {
  const int bx = blockIdx.x;
  const int qt = (bx < 256) ? (63 - (bx >> 3)) : ((bx >> 3) - 32);
  const int kvh = (bx >> 1) & 3, b = bx & 1;
  const int bkv = b * 4 + kvh;
  const int tid = threadIdx.x;
  const int w = tid >> 6, lane = tid & 63;
  const int qd = lane >> 4, c16 = lane & 15;
  const int h = kvh * 4 + w;
  const int q0 = qt * 32;

  // swizzled, stride 64 shorts: row r octet o at r*64 + (o ^ (r&7))*8
  __shared__ __attribute__((aligned(16))) short sK[2][64 * 64];    // [j][d]
  __shared__ __attribute__((aligned(16))) short sVt[2][64 * 64];   // [d][j]
  __shared__ __attribute__((aligned(16))) short sP[4][32 * 72];    // per wave [q32][j64]

  auto stage = [&](int kt, int d) {
#pragma unroll
    for (int i = 0; i < 2; i++) {
      int c = i * 256 + tid;
      int r = c >> 3, cc = c & 7;
      gll16(&QKV[((long)(b * 2048 + kt * 64 + r)) * 1536 + 1024 + kvh * 64 + ((cc ^ (r & 7)) * 8)],
            &sK[d][(i * 256 + w * 64) * 8]);
      gll16(&Vt[((long)(bkv * 64 + r)) * 2048 + kt * 64 + ((cc ^ (r & 7)) * 8)],
            &sVt[d][(i * 256 + w * 64) * 8]);
    }
  };

  stage(0, 0);                        // 4 gll16/thread in flight

  // Q fragments (B-operand: lane c16 = q, octet over d), from global once
  bf16x8 qf[2][2];
#pragma unroll
  for (int s = 0; s < 2; s++) {
    long tok = (long)b * 2048 + q0 + s * 16 + c16;
#pragma unroll
    for (int ks = 0; ks < 2; ks++)
      qf[s][ks] = *(const bf16x8*)(&QKV[tok * 1536 + h * 64 + ks * 32 + qd * 8]);
  }

  f32x4 Ot[2][4] = {};              // O^T: row=d, col=q=c16 (un-normalized)
  float l_i[2] = {0.f, 0.f};        // per-lane partial sums

  const int ntiles = (qt >> 1) + 1;
  for (int kt = 0; kt < ntiles; kt++) {
    const int cur = kt & 1;
    asm volatile("" ::: "memory");
    __builtin_amdgcn_s_barrier();             // buf[cur^1] free (kt-1 compute done)
    if (kt + 1 < ntiles) {
      stage(kt + 1, cur ^ 1);                 // 4 gll16/thread
      asm volatile("s_waitcnt vmcnt(4)" ::: "memory");  // cur tile (and qf) retired
    } else {
      asm volatile("s_waitcnt vmcnt(0)" ::: "memory");
    }
    __builtin_amdgcn_s_barrier();             // all waves' cur data visible
    asm volatile("" ::: "memory");

    // ---- S^T = K Q^T : A = K (c16 = j), B = Q (c16 = q); kf shared by strips ----
    f32x4 St[2][4];
#pragma unroll
    for (int jc = 0; jc < 4; jc++) {
      int rr = jc * 16 + c16;
      bf16x8 kf0 = *(const bf16x8*)(&sK[cur][rr * 64 + ((0 + qd) ^ (c16 & 7)) * 8]);
      bf16x8 kf1 = *(const bf16x8*)(&sK[cur][rr * 64 + ((4 + qd) ^ (c16 & 7)) * 8]);
#pragma unroll
      for (int s = 0; s < 2; s++) {
        f32x4 z = {};
        z = __builtin_amdgcn_mfma_f32_16x16x32_bf16(kf0, qf[s][0], z, 0, 0, 0);
        z = __builtin_amdgcn_mfma_f32_16x16x32_bf16(kf1, qf[s][1], z, 0, 0, 0);
        St[s][jc] = z;
      }
    }

    // ---- causal mask on the diagonal (last) tile only ----
    if (kt == ntiles - 1) {
#pragma unroll
      for (int s = 0; s < 2; s++) {
        int qg = q0 + s * 16 + c16 - kt * 64;   // q rel. to tile
#pragma unroll
        for (int jc = 0; jc < 4; jc++)
#pragma unroll
          for (int r = 0; r < 4; r++)
            if (jc * 16 + qd * 4 + r > qg) St[s][jc][r] = -3e38f;
      }
    }

    // ---- static-max softmax: p = exp2(CSOFT*s - CMAX); per-lane only ----
#pragma unroll
    for (int s = 0; s < 2; s++) {
      float rs = 0.f;
#pragma unroll
      for (int jc = 0; jc < 4; jc++) {
        unsigned u[4];
#pragma unroll
        for (int r = 0; r < 4; r++) {
          float p = exp2f(fmaf(CSOFT, St[s][jc][r], -CMAX));
          u[r] = __builtin_bit_cast(unsigned, p) & 0xffff0000u;   // truncate to bf16
          rs += __builtin_bit_cast(float, u[r]);                  // l from truncated p
        }
        int2 pk;
        pk.x = (int)((u[0] >> 16) | u[1]);
        pk.y = (int)((u[2] >> 16) | u[3]);
        *(int2*)(&sP[w][(s * 16 + c16) * 72 + jc * 16 + qd * 4]) = pk;
      }
      l_i[s] += rs;
    }
    asm volatile("s_waitcnt lgkmcnt(0)" ::: "memory");  // own-wave sP writes retired

    // ---- O^T += V^T P^T : A = Vt (c16 = d), B = P^T (c16 = q); vf shared ----
#pragma unroll
    for (int ks2 = 0; ks2 < 2; ks2++) {
      bf16x8 pf0 = *(const bf16x8*)(&sP[w][(0 + c16) * 72 + ks2 * 32 + qd * 8]);
      bf16x8 pf1 = *(const bf16x8*)(&sP[w][(16 + c16) * 72 + ks2 * 32 + qd * 8]);
#pragma unroll
      for (int dt = 0; dt < 4; dt++) {
        bf16x8 vf = *(const bf16x8*)(&sVt[cur][(dt * 16 + c16) * 64 + (((ks2 * 4 + qd) ^ (c16 & 7)) * 8)]);
        Ot[0][dt] = __builtin_amdgcn_mfma_f32_16x16x32_bf16(vf, pf0, Ot[0][dt], 0, 0, 0);
        Ot[1][dt] = __builtin_amdgcn_mfma_f32_16x16x32_bf16(vf, pf1, Ot[1][dt], 0, 0, 0);
      }
    }
  }

  // ---- epilogue: reduce l across the 4 qd groups, normalize, store O^T ----
#pragma unroll
  for (int s = 0; s < 2; s++) {
    float l = l_i[s];
    l += __shfl_xor(l, 16, 64);
    l += __shfl_xor(l, 32, 64);
    float inv = 1.f / l;
    long tok = (long)b * 2048 + q0 + s * 16 + c16;
#pragma unroll
    for (int dt = 0; dt < 4; dt++) {
      short4 o;
      o.x = f2bf(Ot[s][dt][0] * inv);
      o.y = f2bf(Ot[s][dt][1] * inv);
      o.z = f2bf(Ot[s][dt][2] * inv);
      o.w = f2bf(Ot[s][dt][3] * inv);
      *(short4*)(&Aout[tok * 1024 + h * 64 + dt * 16 + qd * 4]) = o;
    }
  }
}

// ---------- launch ----------
extern "C" void kernel_launch(void* const* d_in, const int* in_sizes, int n_in,
                              void* d_out, int out_size, void* d_ws, size_t ws_size,
                              hipStream_t stream) {
  const float* x   = (const float*)d_in[0];   // [2,2048,1024]
  const float* Wq  = (const float*)d_in[1];   // [1024,1024]
  const float* Wkv = (const float*)d_in[2];   // [1024,512]
  const float* Wo  = (const float*)d_in[3];   // [1024,1024]

  char* ws = (char*)d_ws;
  short* xb    = (short*)(ws);                          //  8,388,608 B (dead after gemm1)
  short* Wqkvt = (short*)(ws + 8388608);                //  3,145,728 B  [1536][1024]
  short* Wot   = (short*)(ws + 11534336);               //  2,097,152 B  [1024][1024]
  short* QKV   = (short*)(ws + 13631488);               // 12,582,912 B  [4096][1536]
  short* attn  = (short*)(ws + 26214400);               //  8,388,608 B  [4096][1024]
  short* Vtb   = (short*)(ws);                          //  4,194,304 B, aliases xb (safe: xb dead)

  convert_bf16<<<4096, 256, 0, stream>>>(x, xb, 4194304);
  prep_weights<<<dim3(32, 32, 3), dim3(32, 8), 0, stream>>>(Wq, Wkv, Wo, Wqkvt, Wot);

  // QKV = xb @ Wqkv   (M=4096, N=1536, K=1024), bf16 out; grid 768 = 3 blocks/CU
  gemm_bt<true><<<dim3(12, 64), 256, 0, stream>>>(xb, Wqkvt, QKV, 1536, 1024);
  // V -> Vt[b][kvh][d][t]  (xb no longer needed; Vtb aliases it)
  transpose_v<<<dim3(64, 2, 8), dim3(32, 8), 0, stream>>>(QKV, Vtb);
  // attention: 512 blocks, makespan-balanced qt order
  attn_kernel<<<dim3(512), 256, 0, stream>>>(QKV, Vtb, attn);
  // out = attn @ Wo   (M=4096, N=1024, K=1024), fp32 out; grid 512 = 2 blocks/CU
  gemm_bt<false><<<dim3(8, 64), 256, 0, stream>>>(attn, Wot, d_out, 1024, 1024);
}

// Round 5
// 163.966 us; speedup vs baseline: 1.9256x; 1.1606x over previous
//
#include <hip/hip_runtime.h>

// ---------- types ----------
using bf16x8 = __attribute__((ext_vector_type(8))) __bf16;
using f32x4  = __attribute__((ext_vector_type(4))) float;

__device__ __forceinline__ short f2bf(float f) {
  unsigned u = __builtin_bit_cast(unsigned, f);
  u += 0x7fffu + ((u >> 16) & 1u);   // RNE
  return (short)(u >> 16);
}

// async global->LDS, 16B per lane; lds base must be wave-uniform
__device__ __forceinline__ void gll16(const void* g, void* l) {
  __builtin_amdgcn_global_load_lds((const __attribute__((address_space(1))) unsigned*)g,
                                   (__attribute__((address_space(3))) unsigned*)l, 16, 0, 0);
}

// ---------- fp32 -> bf16 elementwise ----------
__global__ void convert_bf16(const float* __restrict__ in, short* __restrict__ out, int n) {
  int i = (blockIdx.x * blockDim.x + threadIdx.x) * 4;
  if (i + 3 < n) {
    float4 f = *(const float4*)(&in[i]);
    short4 o;
    o.x = f2bf(f.x); o.y = f2bf(f.y); o.z = f2bf(f.z); o.w = f2bf(f.w);
    *(short4*)(&out[i]) = o;
  }
}

// ---------- all three weight transposes in one launch ----------
__global__ void prep_weights(const float* __restrict__ Wq, const float* __restrict__ Wkv,
                             const float* __restrict__ Wo,
                             short* __restrict__ Wqkvt, short* __restrict__ Wot) {
  __shared__ short tile[32][33];
  const int z = blockIdx.z;
  const float* src; short* dst; int C;
  if (z == 0)      { src = Wq;  dst = Wqkvt;               C = 1024; }
  else if (z == 1) { if (blockIdx.x >= 16) return;
                     src = Wkv; dst = Wqkvt + 1024 * 1024; C = 512;  }
  else             { src = Wo;  dst = Wot;                 C = 1024; }
  int c0 = blockIdx.x * 32, r0 = blockIdx.y * 32;
  for (int i = threadIdx.y; i < 32; i += 8)
    tile[i][threadIdx.x] = f2bf(src[(r0 + i) * C + c0 + threadIdx.x]);
  __syncthreads();
  for (int i = threadIdx.y; i < 32; i += 8)
    dst[(c0 + i) * 1024L + r0 + threadIdx.x] = tile[threadIdx.x][i];
}

// ---------- bf16 V section of QKV -> Vt[b][kvh][d][t] ----------
__global__ void transpose_v(const short* __restrict__ QKV, short* __restrict__ Vt) {
  __shared__ short tile[32][33];
  int tt = blockIdx.x, dt = blockIdx.y, bkv = blockIdx.z;
  int b = bkv >> 2, kvh = bkv & 3;
  int t0 = tt * 32, d0 = dt * 32;
  for (int i = threadIdx.y; i < 32; i += 8)
    tile[i][threadIdx.x] = QKV[((long)(b * 2048 + t0 + i)) * 1536 + 1280 + kvh * 64 + d0 + threadIdx.x];
  __syncthreads();
  for (int i = threadIdx.y; i < 32; i += 8)
    Vt[((long)(bkv * 64 + d0 + i)) * 2048 + t0 + threadIdx.x] = tile[threadIdx.x][i];
}

// ---------- bf16 MFMA GEMM: C[M][N] = A[M][K] * Bt[N][K]^T ----------
// 64x128 tile, BK=64, dbuf gll16 staging, XOR-swizzled LDS (conflict-free
// b128 read phases), raw s_barrier + vmcnt(6) prefetch pipeline.
// 4 waves 2x2, each 32x64; 16 MFMA + 12 ds_read_b128 per wave per iter.
template <bool OUT_BF16>
__global__ __launch_bounds__(256) void gemm_bt(const short* __restrict__ A,
                                               const short* __restrict__ Bt,
                                               void* __restrict__ Cout,
                                               int N, int K) {
  __shared__ __attribute__((aligned(16))) short sA[2][64 * 64];
  __shared__ __attribute__((aligned(16))) short sB[2][128 * 64];
  const int tid  = threadIdx.x;
  const int bm   = blockIdx.y * 64, bn = blockIdx.x * 128;
  const int wave = tid >> 6, lane = tid & 63;
  const int wm = (wave >> 1) * 32, wn = (wave & 1) * 64;
  const int qd = lane >> 4, c16 = lane & 15;

  f32x4 acc[2][4] = {};

  auto stage = [&](int it, int d) {
    int k0 = it * 64;
#pragma unroll
    for (int i = 0; i < 2; i++) {           // A: 64 rows x 8 octets = 512 chunks
      int c = i * 256 + tid;
      int r = c >> 3, cc = c & 7;
      gll16(&A[(bm + r) * (long)K + k0 + ((cc ^ (r & 7)) * 8)],
            &sA[d][(i * 256 + wave * 64) * 8]);
    }
#pragma unroll
    for (int i = 0; i < 4; i++) {           // B: 128 rows x 8 octets = 1024 chunks
      int c = i * 256 + tid;
      int r = c >> 3, cc = c & 7;
      gll16(&Bt[(bn + r) * (long)K + k0 + ((cc ^ (r & 7)) * 8)],
            &sB[d][(i * 256 + wave * 64) * 8]);
    }
  };

  const int niter = K >> 6;
  stage(0, 0);
  for (int it = 0; it < niter; it++) {
    const int cur = it & 1;
    asm volatile("" ::: "memory");
    __builtin_amdgcn_s_barrier();            // buf[cur^1] free (it-1 compute done)
    if (it + 1 < niter) {
      stage(it + 1, cur ^ 1);                // 6 gll16/thread
      asm volatile("s_waitcnt vmcnt(6)" ::: "memory");   // cur's stage retired
    } else {
      asm volatile("s_waitcnt vmcnt(0)" ::: "memory");
    }
    __builtin_amdgcn_s_barrier();            // all waves' cur data visible
    asm volatile("" ::: "memory");

    bf16x8 af[2][2], bfr[4][2];
#pragma unroll
    for (int mt = 0; mt < 2; mt++) {
      int rr = wm + mt * 16 + c16;
#pragma unroll
      for (int ks = 0; ks < 2; ks++)
        af[mt][ks] = *(const bf16x8*)(&sA[cur][rr * 64 + (((ks * 4 + qd) ^ (rr & 7)) * 8)]);
    }
#pragma unroll
    for (int nt = 0; nt < 4; nt++) {
      int rr = wn + nt * 16 + c16;
#pragma unroll
      for (int ks = 0; ks < 2; ks++)
        bfr[nt][ks] = *(const bf16x8*)(&sB[cur][rr * 64 + (((ks * 4 + qd) ^ (rr & 7)) * 8)]);
    }
#pragma unroll
    for (int ks = 0; ks < 2; ks++)
#pragma unroll
      for (int mt = 0; mt < 2; mt++)
#pragma unroll
        for (int nt = 0; nt < 4; nt++)
          acc[mt][nt] = __builtin_amdgcn_mfma_f32_16x16x32_bf16(af[mt][ks], bfr[nt][ks],
                                                                acc[mt][nt], 0, 0, 0);
  }

  // epilogue: C/D layout col=lane&15, row=(lane>>4)*4+reg  [m89-verified]
#pragma unroll
  for (int mt = 0; mt < 2; mt++)
#pragma unroll
    for (int nt = 0; nt < 4; nt++)
#pragma unroll
      for (int r = 0; r < 4; r++) {
        long row = bm + wm + mt * 16 + qd * 4 + r;
        long col = bn + wn + nt * 16 + c16;
        float v = acc[mt][nt][r];
        if constexpr (OUT_BF16) ((short*)Cout)[row * N + col] = f2bf(v);
        else                    ((float*)Cout)[row * N + col] = v;
      }
}

// ---------- flash attention v5: 16 q/wave, 3 blocks/CU, dbuf prefetch ----------
// Flat grid 1024. bx<512: qt16 = 127-(bx>>3) (long, desc); else (bx>>3)-64
// (short, asc). Block = 4 waves = the 4 Q-heads of kv-group kvh; each wave
// owns 16 q rows (q = lane&15), q0 = qt16*16. S^T orientation.
#define CSOFT 0.18033688f            // (1/sqrt(64)) * log2(e)
#define CMAX  (CSOFT * 12.0f)        // static shift; softmax shift-invariant

__global__ __launch_bounds__(256) void attn_kernel(const short* __restrict__ QKV,
                                                   const short* __restrict__ Vt,
                                                   short* __restrict__ Aout) {
  const int bx = blockIdx.x;
  const int qt = (bx < 512) ? (127 - (bx >> 3)) : ((bx >> 3) - 64);
  const int kvh = (bx >> 1) & 3, b = bx & 1;
  const int bkv = b * 4 + kvh;
  const int tid = threadIdx.x;
  const int w = tid >> 6, lane = tid & 63;
  const int qd = lane >> 4, c16 = lane & 15;
  const int h = kvh * 4 + w;
  const int q0 = qt * 16;

  // swizzled, stride 64 shorts: row r octet o at r*64 + (o ^ (r&7))*8
  __shared__ __attribute__((aligned(16))) short sK[2][64 * 64];    // [j][d]
  __shared__ __attribute__((aligned(16))) short sVt[2][64 * 64];   // [d][j]
  __shared__ __attribute__((aligned(16))) short sP[4][16 * 72];    // per wave [q16][j64]

  auto stage = [&](int kt, int d) {
#pragma unroll
    for (int i = 0; i < 2; i++) {
      int c = i * 256 + tid;
      int r = c >> 3, cc = c & 7;
      gll16(&QKV[((long)(b * 2048 + kt * 64 + r)) * 1536 + 1024 + kvh * 64 + ((cc ^ (r & 7)) * 8)],
            &sK[d][(i * 256 + w * 64) * 8]);
      gll16(&Vt[((long)(bkv * 64 + r)) * 2048 + kt * 64 + ((cc ^ (r & 7)) * 8)],
            &sVt[d][(i * 256 + w * 64) * 8]);
    }
  };

  stage(0, 0);                        // 4 gll16/thread in flight

  // Q fragments (B-operand: lane c16 = q, octet over d), from global once
  bf16x8 qf[2];
  {
    long tok = (long)b * 2048 + q0 + c16;
#pragma unroll
    for (int ks = 0; ks < 2; ks++)
      qf[ks] = *(const bf16x8*)(&QKV[tok * 1536 + h * 64 + ks * 32 + qd * 8]);
  }

  f32x4 Ot[4] = {};                 // O^T: row=d, col=q=c16 (un-normalized)
  float l_i = 0.f;                  // per-lane partial sum

  const int ntiles = (qt >> 2) + 1;
  for (int kt = 0; kt < ntiles; kt++) {
    const int cur = kt & 1;
    asm volatile("" ::: "memory");
    __builtin_amdgcn_s_barrier();             // buf[cur^1] free (kt-1 compute done)
    if (kt + 1 < ntiles) {
      stage(kt + 1, cur ^ 1);                 // 4 gll16/thread
      asm volatile("s_waitcnt vmcnt(4)" ::: "memory");  // cur tile + qf retired
    } else {
      asm volatile("s_waitcnt vmcnt(0)" ::: "memory");
    }
    __builtin_amdgcn_s_barrier();             // all waves' cur data visible
    asm volatile("" ::: "memory");

    // ---- S^T = K Q^T : A = K (c16 = j), B = Q (c16 = q) ----
    f32x4 St[4];
#pragma unroll
    for (int jc = 0; jc < 4; jc++) {
      int rr = jc * 16 + c16;
      bf16x8 kf0 = *(const bf16x8*)(&sK[cur][rr * 64 + ((0 + qd) ^ (rr & 7)) * 8]);
      bf16x8 kf1 = *(const bf16x8*)(&sK[cur][rr * 64 + ((4 + qd) ^ (rr & 7)) * 8]);
      f32x4 z = {};
      z = __builtin_amdgcn_mfma_f32_16x16x32_bf16(kf0, qf[0], z, 0, 0, 0);
      z = __builtin_amdgcn_mfma_f32_16x16x32_bf16(kf1, qf[1], z, 0, 0, 0);
      St[jc] = z;
    }

    // ---- causal mask on the diagonal (last) tile only ----
    if (kt == ntiles - 1) {
      int qg = q0 + c16 - kt * 64;            // q relative to tile
#pragma unroll
      for (int jc = 0; jc < 4; jc++)
#pragma unroll
        for (int r = 0; r < 4; r++)
          if (jc * 16 + qd * 4 + r > qg) St[jc][r] = -3e38f;
    }

    // ---- static-max softmax: p = exp2(CSOFT*s - CMAX); per-lane only ----
    {
      float rs = 0.f;
#pragma unroll
      for (int jc = 0; jc < 4; jc++) {
        unsigned u[4];
#pragma unroll
        for (int r = 0; r < 4; r++) {
          float p = exp2f(fmaf(CSOFT, St[jc][r], -CMAX));
          u[r] = __builtin_bit_cast(unsigned, p) & 0xffff0000u;   // truncate to bf16
          rs += __builtin_bit_cast(float, u[r]);                  // l from truncated p
        }
        int2 pk;
        pk.x = (int)((u[0] >> 16) | u[1]);
        pk.y = (int)((u[2] >> 16) | u[3]);
        *(int2*)(&sP[w][c16 * 72 + jc * 16 + qd * 4]) = pk;
      }
      l_i += rs;
    }
    asm volatile("s_waitcnt lgkmcnt(0)" ::: "memory");  // own-wave sP writes retired

    // ---- O^T += V^T P^T : A = Vt (c16 = d), B = P^T (c16 = q) ----
#pragma unroll
    for (int ks2 = 0; ks2 < 2; ks2++) {
      bf16x8 pf = *(const bf16x8*)(&sP[w][c16 * 72 + ks2 * 32 + qd * 8]);
#pragma unroll
      for (int dt = 0; dt < 4; dt++) {
        int rr = dt * 16 + c16;
        bf16x8 vf = *(const bf16x8*)(&sVt[cur][rr * 64 + (((ks2 * 4 + qd) ^ (rr & 7)) * 8)]);
        Ot[dt] = __builtin_amdgcn_mfma_f32_16x16x32_bf16(vf, pf, Ot[dt], 0, 0, 0);
      }
    }
  }

  // ---- epilogue: reduce l across the 4 qd groups, normalize, store O^T ----
  {
    float l = l_i;
    l += __shfl_xor(l, 16, 64);
    l += __shfl_xor(l, 32, 64);
    float inv = 1.f / l;
    long tok = (long)b * 2048 + q0 + c16;
#pragma unroll
    for (int dt = 0; dt < 4; dt++) {
      short4 o;
      o.x = f2bf(Ot[dt][0] * inv);
      o.y = f2bf(Ot[dt][1] * inv);
      o.z = f2bf(Ot[dt][2] * inv);
      o.w = f2bf(Ot[dt][3] * inv);
      *(short4*)(&Aout[tok * 1024 + h * 64 + dt * 16 + qd * 4]) = o;
    }
  }
}

// ---------- launch ----------
extern "C" void kernel_launch(void* const* d_in, const int* in_sizes, int n_in,
                              void* d_out, int out_size, void* d_ws, size_t ws_size,
                              hipStream_t stream) {
  const float* x   = (const float*)d_in[0];   // [2,2048,1024]
  const float* Wq  = (const float*)d_in[1];   // [1024,1024]
  const float* Wkv = (const float*)d_in[2];   // [1024,512]
  const float* Wo  = (const float*)d_in[3];   // [1024,1024]

  char* ws = (char*)d_ws;
  short* xb    = (short*)(ws);                          //  8,388,608 B (dead after gemm1)
  short* Wqkvt = (short*)(ws + 8388608);                //  3,145,728 B  [1536][1024]
  short* Wot   = (short*)(ws + 11534336);               //  2,097,152 B  [1024][1024]
  short* QKV   = (short*)(ws + 13631488);               // 12,582,912 B  [4096][1536]
  short* attn  = (short*)(ws + 26214400);               //  8,388,608 B  [4096][1024]
  short* Vtb   = (short*)(ws);                          //  4,194,304 B, aliases xb (safe: xb dead)

  convert_bf16<<<4096, 256, 0, stream>>>(x, xb, 4194304);
  prep_weights<<<dim3(32, 32, 3), dim3(32, 8), 0, stream>>>(Wq, Wkv, Wo, Wqkvt, Wot);

  // QKV = xb @ Wqkv   (M=4096, N=1536, K=1024), bf16 out; grid 768 = 3 blocks/CU
  gemm_bt<true><<<dim3(12, 64), 256, 0, stream>>>(xb, Wqkvt, QKV, 1536, 1024);
  // V -> Vt[b][kvh][d][t]  (xb no longer needed; Vtb aliases it)
  transpose_v<<<dim3(64, 2, 8), dim3(32, 8), 0, stream>>>(QKV, Vtb);
  // attention: 1024 blocks, 16 q/wave, makespan-balanced qt order
  attn_kernel<<<dim3(1024), 256, 0, stream>>>(QKV, Vtb, attn);
  // out = attn @ Wo   (M=4096, N=1024, K=1024), fp32 out; grid 512 = 2 blocks/CU
  gemm_bt<false><<<dim3(8, 64), 256, 0, stream>>>(attn, Wot, d_out, 1024, 1024);
}

// Round 6
// 157.417 us; speedup vs baseline: 2.0057x; 1.0416x over previous
//
#include <hip/hip_runtime.h>

// ---------- types ----------
using bf16x8 = __attribute__((ext_vector_type(8))) __bf16;
using f32x4  = __attribute__((ext_vector_type(4))) float;

__device__ __forceinline__ short f2bf(float f) {
  unsigned u = __builtin_bit_cast(unsigned, f);
  u += 0x7fffu + ((u >> 16) & 1u);   // RNE
  return (short)(u >> 16);
}

// async global->LDS, 16B per lane; lds base must be wave-uniform
__device__ __forceinline__ void gll16(const void* g, void* l) {
  __builtin_amdgcn_global_load_lds((const __attribute__((address_space(1))) unsigned*)g,
                                   (__attribute__((address_space(3))) unsigned*)l, 16, 0, 0);
}

// ---------- fused preprocessing: x->bf16 + all 3 weight transposes ----------
// grid 6656: [0,4096) convert x; [4096,5120) Wq; [5120,5632) Wkv; [5632,6656) Wo
__global__ __launch_bounds__(256) void fused_pre(const float* __restrict__ x,
                                                 const float* __restrict__ Wq,
                                                 const float* __restrict__ Wkv,
                                                 const float* __restrict__ Wo,
                                                 short* __restrict__ xb,
                                                 short* __restrict__ Wqkvt,
                                                 short* __restrict__ Wot) {
  const int bx = blockIdx.x, tid = threadIdx.x;
  if (bx < 4096) {
    int i = (bx * 256 + tid) * 4;
    float4 f = *(const float4*)(&x[i]);
    short4 o;
    o.x = f2bf(f.x); o.y = f2bf(f.y); o.z = f2bf(f.z); o.w = f2bf(f.w);
    *(short4*)(&xb[i]) = o;
    return;
  }
  __shared__ short tile[32][33];
  const float* src; short* dst; int C, ti;
  if (bx < 5120)      { src = Wq;  dst = Wqkvt;               C = 1024; ti = bx - 4096; }
  else if (bx < 5632) { src = Wkv; dst = Wqkvt + 1024 * 1024; C = 512;  ti = bx - 5120; }
  else                { src = Wo;  dst = Wot;                 C = 1024; ti = bx - 5632; }
  int ctiles = C >> 5;
  int c0 = (ti % ctiles) * 32, r0 = (ti / ctiles) * 32;
  int tx = tid & 31, ty = tid >> 5;
  for (int i = ty; i < 32; i += 8)
    tile[i][tx] = f2bf(src[(r0 + i) * C + c0 + tx]);
  __syncthreads();
  for (int i = ty; i < 32; i += 8)
    dst[(c0 + i) * 1024L + r0 + tx] = tile[tx][i];
}

// ---------- bf16 MFMA GEMM: C[M][N] = A[M][K] * Bt[N][K]^T ----------
// 64x128 tile, BK=64, dbuf gll16 staging, XOR-swizzled LDS, raw s_barrier +
// vmcnt(6) prefetch. WRITE_VT: for cols>=1280 (V section) also emit
// Vt[b][kvh][d][t] (registers already hold t-contiguous quads).
template <bool OUT_BF16, bool WRITE_VT>
__global__ __launch_bounds__(256) void gemm_bt(const short* __restrict__ A,
                                               const short* __restrict__ Bt,
                                               void* __restrict__ Cout,
                                               short* __restrict__ Vt,
                                               int N, int K) {
  __shared__ __attribute__((aligned(16))) short sA[2][64 * 64];
  __shared__ __attribute__((aligned(16))) short sB[2][128 * 64];
  const int tid  = threadIdx.x;
  const int bm   = blockIdx.y * 64, bn = blockIdx.x * 128;
  const int wave = tid >> 6, lane = tid & 63;
  const int wm = (wave >> 1) * 32, wn = (wave & 1) * 64;
  const int qd = lane >> 4, c16 = lane & 15;

  f32x4 acc[2][4] = {};

  auto stage = [&](int it, int d) {
    int k0 = it * 64;
#pragma unroll
    for (int i = 0; i < 2; i++) {           // A: 64 rows x 8 octets
      int c = i * 256 + tid;
      int r = c >> 3, cc = c & 7;
      gll16(&A[(bm + r) * (long)K + k0 + ((cc ^ (r & 7)) * 8)],
            &sA[d][(i * 256 + wave * 64) * 8]);
    }
#pragma unroll
    for (int i = 0; i < 4; i++) {           // B: 128 rows x 8 octets
      int c = i * 256 + tid;
      int r = c >> 3, cc = c & 7;
      gll16(&Bt[(bn + r) * (long)K + k0 + ((cc ^ (r & 7)) * 8)],
            &sB[d][(i * 256 + wave * 64) * 8]);
    }
  };

  const int niter = K >> 6;
  stage(0, 0);
  for (int it = 0; it < niter; it++) {
    const int cur = it & 1;
    asm volatile("" ::: "memory");
    __builtin_amdgcn_s_barrier();            // buf[cur^1] free
    if (it + 1 < niter) {
      stage(it + 1, cur ^ 1);                // 6 gll16/thread
      asm volatile("s_waitcnt vmcnt(6)" ::: "memory");
    } else {
      asm volatile("s_waitcnt vmcnt(0)" ::: "memory");
    }
    __builtin_amdgcn_s_barrier();            // cur data visible
    asm volatile("" ::: "memory");

    bf16x8 af[2][2], bfr[4][2];
#pragma unroll
    for (int mt = 0; mt < 2; mt++) {
      int rr = wm + mt * 16 + c16;
#pragma unroll
      for (int ks = 0; ks < 2; ks++)
        af[mt][ks] = *(const bf16x8*)(&sA[cur][rr * 64 + (((ks * 4 + qd) ^ (rr & 7)) * 8)]);
    }
#pragma unroll
    for (int nt = 0; nt < 4; nt++) {
      int rr = wn + nt * 16 + c16;
#pragma unroll
      for (int ks = 0; ks < 2; ks++)
        bfr[nt][ks] = *(const bf16x8*)(&sB[cur][rr * 64 + (((ks * 4 + qd) ^ (rr & 7)) * 8)]);
    }
#pragma unroll
    for (int ks = 0; ks < 2; ks++)
#pragma unroll
      for (int mt = 0; mt < 2; mt++)
#pragma unroll
        for (int nt = 0; nt < 4; nt++)
          acc[mt][nt] = __builtin_amdgcn_mfma_f32_16x16x32_bf16(af[mt][ks], bfr[nt][ks],
                                                                acc[mt][nt], 0, 0, 0);
  }

  // epilogue: C/D layout col=lane&15, row=(lane>>4)*4+reg  [m89-verified]
#pragma unroll
  for (int mt = 0; mt < 2; mt++)
#pragma unroll
    for (int nt = 0; nt < 4; nt++) {
      long row0 = bm + wm + mt * 16 + qd * 4;
      long col  = bn + wn + nt * 16 + c16;
      short4 p;
#pragma unroll
      for (int r = 0; r < 4; r++) {
        float v = acc[mt][nt][r];
        if constexpr (OUT_BF16) ((short*)Cout)[(row0 + r) * N + col] = f2bf(v);
        else                    ((float*)Cout)[(row0 + r) * N + col] = v;
        if constexpr (WRITE_VT)
          ((short*)&p)[r] = f2bf(v);
      }
      if constexpr (WRITE_VT) {
        if (col >= 1280) {                    // V section -> Vt[b*4+kvh][d][t]
          int d = (int)col - 1280;            // kvh = d>>6, dd = d&63
          int b = (int)(row0 >> 11), t = (int)(row0 & 2047);
          *(short4*)(&Vt[((long)(b * 256 + d)) * 2048 + t]) = p;
        }
      }
    }
}

// ---------- flash attention v6: 4 blocks/CU fully resident ----------
// Flat grid 1024. bx<512: qt = 127-(bx>>3) (long, desc); else (bx>>3)-64.
// Block = 4 waves = 4 Q-heads of kv-group kvh; wave owns 16 q rows
// (q = lane&15), q0 = qt*16. S^T orientation. sK dbuf (prefetch), sVt
// single-buffered (staged same-iter; latency overlaps S+softmax).
#define CSOFT 0.18033688f            // (1/sqrt(64)) * log2(e)
#define CMAX  (CSOFT * 12.0f)        // static shift; softmax shift-invariant

__global__ __launch_bounds__(256, 4) void attn_kernel(const short* __restrict__ QKV,
                                                      const short* __restrict__ Vt,
                                                      short* __restrict__ Aout) {
  const int bx = blockIdx.x;
  const int qt = (bx < 512) ? (127 - (bx >> 3)) : ((bx >> 3) - 64);
  const int kvh = (bx >> 1) & 3, b = bx & 1;
  const int bkv = b * 4 + kvh;
  const int tid = threadIdx.x;
  const int w = tid >> 6, lane = tid & 63;
  const int qd = lane >> 4, c16 = lane & 15;
  const int h = kvh * 4 + w;
  const int q0 = qt * 16;

  // swizzled, stride 64 shorts: row r octet o at r*64 + (o ^ (r&7))*8
  __shared__ __attribute__((aligned(16))) short sK[2][64 * 64];    // [j][d] dbuf
  __shared__ __attribute__((aligned(16))) short sVt[64 * 64];      // [d][j] single
  __shared__ __attribute__((aligned(16))) short sP[4][16 * 72];    // per wave [q16][j64]
  // total 16K + 8K + 9K = 33K -> 4 blocks/CU

  auto stageK = [&](int kt, int d) {
#pragma unroll
    for (int i = 0; i < 2; i++) {
      int c = i * 256 + tid;
      int r = c >> 3, cc = c & 7;
      gll16(&QKV[((long)(b * 2048 + kt * 64 + r)) * 1536 + 1024 + kvh * 64 + ((cc ^ (r & 7)) * 8)],
            &sK[d][(i * 256 + w * 64) * 8]);
    }
  };
  auto stageV = [&](int kt) {
#pragma unroll
    for (int i = 0; i < 2; i++) {
      int c = i * 256 + tid;
      int r = c >> 3, cc = c & 7;
      gll16(&Vt[((long)(bkv * 64 + r)) * 2048 + kt * 64 + ((cc ^ (r & 7)) * 8)],
            &sVt[(i * 256 + w * 64) * 8]);
    }
  };

  stageK(0, 0);                       // 2 gll16/thread in flight

  // Q fragments (B-operand: lane c16 = q, octet over d), from global once
  bf16x8 qf[2];
  {
    long tok = (long)b * 2048 + q0 + c16;
#pragma unroll
    for (int ks = 0; ks < 2; ks++)
      qf[ks] = *(const bf16x8*)(&QKV[tok * 1536 + h * 64 + ks * 32 + qd * 8]);
  }

  f32x4 Ot[4] = {};                 // O^T: row=d, col=q=c16 (un-normalized)
  float l_i = 0.f;                  // per-lane partial sum

  const int ntiles = (qt >> 2) + 1;
  for (int kt = 0; kt < ntiles; kt++) {
    const int cur = kt & 1;
    asm volatile("" ::: "memory");
    __builtin_amdgcn_s_barrier();             // prev compute done: sVt & sK[cur^1] free
    stageV(kt);                               // 2 gll (waited before PV)
    if (kt + 1 < ntiles) {
      stageK(kt + 1, cur ^ 1);                // 2 gll
      asm volatile("s_waitcnt vmcnt(4)" ::: "memory");  // prior K staging retired
    } else {
      asm volatile("s_waitcnt vmcnt(2)" ::: "memory");
    }
    __builtin_amdgcn_s_barrier();             // sK[cur] visible to all waves
    asm volatile("" ::: "memory");

    // ---- S^T = K Q^T : A = K (c16 = j), B = Q (c16 = q) ----
    f32x4 St[4];
#pragma unroll
    for (int jc = 0; jc < 4; jc++) {
      int rr = jc * 16 + c16;
      bf16x8 kf0 = *(const bf16x8*)(&sK[cur][rr * 64 + ((0 + qd) ^ (rr & 7)) * 8]);
      bf16x8 kf1 = *(const bf16x8*)(&sK[cur][rr * 64 + ((4 + qd) ^ (rr & 7)) * 8]);
      f32x4 z = {};
      z = __builtin_amdgcn_mfma_f32_16x16x32_bf16(kf0, qf[0], z, 0, 0, 0);
      z = __builtin_amdgcn_mfma_f32_16x16x32_bf16(kf1, qf[1], z, 0, 0, 0);
      St[jc] = z;
    }

    // ---- causal mask on the diagonal (last) tile only ----
    if (kt == ntiles - 1) {
      int qg = q0 + c16 - kt * 64;            // q relative to tile
#pragma unroll
      for (int jc = 0; jc < 4; jc++)
#pragma unroll
        for (int r = 0; r < 4; r++)
          if (jc * 16 + qd * 4 + r > qg) St[jc][r] = -3e38f;
    }

    // ---- static-max softmax: p = exp2(CSOFT*s - CMAX); per-lane only ----
    {
      float rs = 0.f;
#pragma unroll
      for (int jc = 0; jc < 4; jc++) {
        unsigned u[4];
#pragma unroll
        for (int r = 0; r < 4; r++) {
          float p = exp2f(fmaf(CSOFT, St[jc][r], -CMAX));
          u[r] = __builtin_bit_cast(unsigned, p) & 0xffff0000u;   // truncate to bf16
          rs += __builtin_bit_cast(float, u[r]);                  // l from truncated p
        }
        int2 pk;
        pk.x = (int)((u[0] >> 16) | u[1]);
        pk.y = (int)((u[2] >> 16) | u[3]);
        *(int2*)(&sP[w][c16 * 72 + jc * 16 + qd * 4]) = pk;
      }
      l_i += rs;
    }
    asm volatile("s_waitcnt lgkmcnt(0)" ::: "memory");  // own sP writes retired

    // V tile arrived? (own gll) then barrier so ALL waves' chunks are in
    if (kt + 1 < ntiles) asm volatile("s_waitcnt vmcnt(2)" ::: "memory");
    else                 asm volatile("s_waitcnt vmcnt(0)" ::: "memory");
    __builtin_amdgcn_s_barrier();
    asm volatile("" ::: "memory");

    // ---- O^T += V^T P^T : A = Vt (c16 = d), B = P^T (c16 = q) ----
#pragma unroll
    for (int ks2 = 0; ks2 < 2; ks2++) {
      bf16x8 pf = *(const bf16x8*)(&sP[w][c16 * 72 + ks2 * 32 + qd * 8]);
#pragma unroll
      for (int dt = 0; dt < 4; dt++) {
        int rr = dt * 16 + c16;
        bf16x8 vf = *(const bf16x8*)(&sVt[rr * 64 + (((ks2 * 4 + qd) ^ (rr & 7)) * 8)]);
        Ot[dt] = __builtin_amdgcn_mfma_f32_16x16x32_bf16(vf, pf, Ot[dt], 0, 0, 0);
      }
    }
  }

  // ---- epilogue: reduce l across the 4 qd groups, normalize, store O^T ----
  {
    float l = l_i;
    l += __shfl_xor(l, 16, 64);
    l += __shfl_xor(l, 32, 64);
    float inv = 1.f / l;
    long tok = (long)b * 2048 + q0 + c16;
#pragma unroll
    for (int dt = 0; dt < 4; dt++) {
      short4 o;
      o.x = f2bf(Ot[dt][0] * inv);
      o.y = f2bf(Ot[dt][1] * inv);
      o.z = f2bf(Ot[dt][2] * inv);
      o.w = f2bf(Ot[dt][3] * inv);
      *(short4*)(&Aout[tok * 1024 + h * 64 + dt * 16 + qd * 4]) = o;
    }
  }
}

// ---------- launch ----------
extern "C" void kernel_launch(void* const* d_in, const int* in_sizes, int n_in,
                              void* d_out, int out_size, void* d_ws, size_t ws_size,
                              hipStream_t stream) {
  const float* x   = (const float*)d_in[0];   // [2,2048,1024]
  const float* Wq  = (const float*)d_in[1];   // [1024,1024]
  const float* Wkv = (const float*)d_in[2];   // [1024,512]
  const float* Wo  = (const float*)d_in[3];   // [1024,1024]

  char* ws = (char*)d_ws;
  short* xb    = (short*)(ws);                          //  8,388,608 B
  short* Wqkvt = (short*)(ws + 8388608);                //  3,145,728 B  [1536][1024]
  short* Wot   = (short*)(ws + 11534336);               //  2,097,152 B  [1024][1024]
  short* QKV   = (short*)(ws + 13631488);               // 12,582,912 B  [4096][1536]
  short* attn  = (short*)(ws + 26214400);               //  8,388,608 B  [4096][1024]
  short* Vtb   = (short*)d_out;                         //  4,194,304 B scratch in d_out
                                                        //  (gemm2 overwrites ALL of d_out)

  // preprocessing: x->bf16 + weight transposes, one launch
  fused_pre<<<dim3(6656), 256, 0, stream>>>(x, Wq, Wkv, Wo, xb, Wqkvt, Wot);

  // QKV = xb @ Wqkv  (M=4096,N=1536,K=1024), bf16 out + fused V-transpose
  gemm_bt<true, true><<<dim3(12, 64), 256, 0, stream>>>(xb, Wqkvt, QKV, Vtb, 1536, 1024);

  // attention: 1024 blocks = 4/CU fully resident, balanced qt order
  attn_kernel<<<dim3(1024), 256, 0, stream>>>(QKV, Vtb, attn);

  // out = attn @ Wo  (M=4096,N=1024,K=1024), fp32 out
  gemm_bt<false, false><<<dim3(8, 64), 256, 0, stream>>>(attn, Wot, d_out, nullptr, 1024, 1024);
}

// Round 7
// 156.243 us; speedup vs baseline: 2.0208x; 1.0075x over previous
//
#include <hip/hip_runtime.h>

// ---------- types ----------
using bf16x8 = __attribute__((ext_vector_type(8))) __bf16;
using f32x4  = __attribute__((ext_vector_type(4))) float;

__device__ __forceinline__ short f2bf(float f) {
  unsigned u = __builtin_bit_cast(unsigned, f);
  u += 0x7fffu + ((u >> 16) & 1u);   // RNE
  return (short)(u >> 16);
}

// async global->LDS, 16B per lane; lds base must be wave-uniform
__device__ __forceinline__ void gll16(const void* g, void* l) {
  __builtin_amdgcn_global_load_lds((const __attribute__((address_space(1))) unsigned*)g,
                                   (__attribute__((address_space(3))) unsigned*)l, 16, 0, 0);
}

// ---------- fused preprocessing: x->bf16 + all 3 weight transposes ----------
// grid 6656: [0,4096) convert x; [4096,5120) Wq; [5120,5632) Wkv; [5632,6656) Wo
__global__ __launch_bounds__(256) void fused_pre(const float* __restrict__ x,
                                                 const float* __restrict__ Wq,
                                                 const float* __restrict__ Wkv,
                                                 const float* __restrict__ Wo,
                                                 short* __restrict__ xb,
                                                 short* __restrict__ Wqkvt,
                                                 short* __restrict__ Wot) {
  const int bx = blockIdx.x, tid = threadIdx.x;
  if (bx < 4096) {
    int i = (bx * 256 + tid) * 4;
    float4 f = *(const float4*)(&x[i]);
    short4 o;
    o.x = f2bf(f.x); o.y = f2bf(f.y); o.z = f2bf(f.z); o.w = f2bf(f.w);
    *(short4*)(&xb[i]) = o;
    return;
  }
  __shared__ short tile[32][33];
  const float* src; short* dst; int C, ti;
  if (bx < 5120)      { src = Wq;  dst = Wqkvt;               C = 1024; ti = bx - 4096; }
  else if (bx < 5632) { src = Wkv; dst = Wqkvt + 1024 * 1024; C = 512;  ti = bx - 5120; }
  else                { src = Wo;  dst = Wot;                 C = 1024; ti = bx - 5632; }
  int ctiles = C >> 5;
  int c0 = (ti % ctiles) * 32, r0 = (ti / ctiles) * 32;
  int tx = tid & 31, ty = tid >> 5;
  for (int i = ty; i < 32; i += 8)
    tile[i][tx] = f2bf(src[(r0 + i) * C + c0 + tx]);
  __syncthreads();
  for (int i = ty; i < 32; i += 8)
    dst[(c0 + i) * 1024L + r0 + tx] = tile[tx][i];
}

// ---------- bf16 MFMA GEMM: C[M][N] = A[M][K] * Bt[N][K]^T ----------
// Block tile 64 x (32*NT), BK=64, dbuf gll16 staging, XOR-swizzled LDS,
// raw s_barrier + vmcnt(2+NT) prefetch. 4 waves 2x2, each 32 x (16*NT).
// NT chosen so grid = 1024 = 4 blocks/CU fully resident, uniform length.
// WRITE_VT: cols>=1280 (V section) also emit Vt[b][kvh][d][t].
template <int NT, bool OUT_BF16, bool WRITE_VT>
__global__ __launch_bounds__(256) void gemm_bt(const short* __restrict__ A,
                                               const short* __restrict__ Bt,
                                               void* __restrict__ Cout,
                                               short* __restrict__ Vt,
                                               int N, int K) {
  __shared__ __attribute__((aligned(16))) short sA[2][64 * 64];
  __shared__ __attribute__((aligned(16))) short sB[2][32 * NT * 64];
  const int tid  = threadIdx.x;
  const int bm   = blockIdx.y * 64, bn = blockIdx.x * (32 * NT);
  const int wave = tid >> 6, lane = tid & 63;
  const int wm = (wave >> 1) * 32, wn = (wave & 1) * (16 * NT);
  const int qd = lane >> 4, c16 = lane & 15;

  f32x4 acc[2][NT] = {};

  auto stage = [&](int it, int d) {
    int k0 = it * 64;
#pragma unroll
    for (int i = 0; i < 2; i++) {           // A: 64 rows x 8 octets
      int c = i * 256 + tid;
      int r = c >> 3, cc = c & 7;
      gll16(&A[(bm + r) * (long)K + k0 + ((cc ^ (r & 7)) * 8)],
            &sA[d][(i * 256 + wave * 64) * 8]);
    }
#pragma unroll
    for (int i = 0; i < NT; i++) {          // B: 32*NT rows x 8 octets
      int c = i * 256 + tid;
      int r = c >> 3, cc = c & 7;
      gll16(&Bt[(bn + r) * (long)K + k0 + ((cc ^ (r & 7)) * 8)],
            &sB[d][(i * 256 + wave * 64) * 8]);
    }
  };

  const int niter = K >> 6;
  stage(0, 0);
  for (int it = 0; it < niter; it++) {
    const int cur = it & 1;
    asm volatile("" ::: "memory");
    __builtin_amdgcn_s_barrier();            // buf[cur^1] free
    if (it + 1 < niter) {
      stage(it + 1, cur ^ 1);                // 2+NT gll16/thread
      if constexpr (NT == 3) asm volatile("s_waitcnt vmcnt(5)" ::: "memory");
      else                   asm volatile("s_waitcnt vmcnt(4)" ::: "memory");
    } else {
      asm volatile("s_waitcnt vmcnt(0)" ::: "memory");
    }
    __builtin_amdgcn_s_barrier();            // cur data visible
    asm volatile("" ::: "memory");

    bf16x8 af[2][2], bfr[NT][2];
#pragma unroll
    for (int mt = 0; mt < 2; mt++) {
      int rr = wm + mt * 16 + c16;
#pragma unroll
      for (int ks = 0; ks < 2; ks++)
        af[mt][ks] = *(const bf16x8*)(&sA[cur][rr * 64 + (((ks * 4 + qd) ^ (rr & 7)) * 8)]);
    }
#pragma unroll
    for (int nt = 0; nt < NT; nt++) {
      int rr = wn + nt * 16 + c16;
#pragma unroll
      for (int ks = 0; ks < 2; ks++)
        bfr[nt][ks] = *(const bf16x8*)(&sB[cur][rr * 64 + (((ks * 4 + qd) ^ (rr & 7)) * 8)]);
    }
#pragma unroll
    for (int ks = 0; ks < 2; ks++)
#pragma unroll
      for (int mt = 0; mt < 2; mt++)
#pragma unroll
        for (int nt = 0; nt < NT; nt++)
          acc[mt][nt] = __builtin_amdgcn_mfma_f32_16x16x32_bf16(af[mt][ks], bfr[nt][ks],
                                                                acc[mt][nt], 0, 0, 0);
  }

  // epilogue: C/D layout col=lane&15, row=(lane>>4)*4+reg  [m89-verified]
#pragma unroll
  for (int mt = 0; mt < 2; mt++)
#pragma unroll
    for (int nt = 0; nt < NT; nt++) {
      long row0 = bm + wm + mt * 16 + qd * 4;
      long col  = bn + wn + nt * 16 + c16;
      short4 p;
#pragma unroll
      for (int r = 0; r < 4; r++) {
        float v = acc[mt][nt][r];
        if constexpr (OUT_BF16) ((short*)Cout)[(row0 + r) * N + col] = f2bf(v);
        else                    ((float*)Cout)[(row0 + r) * N + col] = v;
        if constexpr (WRITE_VT)
          ((short*)&p)[r] = f2bf(v);
      }
      if constexpr (WRITE_VT) {
        if (col >= 1280) {                    // V section -> Vt[b*4+kvh][d][t]
          int d = (int)col - 1280;            // kvh = d>>6, dd = d&63
          int b = (int)(row0 >> 11), t = (int)(row0 & 2047);
          *(short4*)(&Vt[((long)(b * 256 + d)) * 2048 + t]) = p;
        }
      }
    }
}

// ---------- flash attention v6: 4 blocks/CU fully resident ----------
// Flat grid 1024. bx<512: qt = 127-(bx>>3) (long, desc); else (bx>>3)-64.
// Block = 4 waves = 4 Q-heads of kv-group kvh; wave owns 16 q rows
// (q = lane&15), q0 = qt*16. S^T orientation. sK dbuf (prefetch), sVt
// single-buffered (staged same-iter; latency overlaps S+softmax).
#define CSOFT 0.18033688f            // (1/sqrt(64)) * log2(e)
#define CMAX  (CSOFT * 12.0f)        // static shift; softmax shift-invariant

__global__ __launch_bounds__(256, 4) void attn_kernel(const short* __restrict__ QKV,
                                                      const short* __restrict__ Vt,
                                                      short* __restrict__ Aout) {
  const int bx = blockIdx.x;
  const int qt = (bx < 512) ? (127 - (bx >> 3)) : ((bx >> 3) - 64);
  const int kvh = (bx >> 1) & 3, b = bx & 1;
  const int bkv = b * 4 + kvh;
  const int tid = threadIdx.x;
  const int w = tid >> 6, lane = tid & 63;
  const int qd = lane >> 4, c16 = lane & 15;
  const int h = kvh * 4 + w;
  const int q0 = qt * 16;

  // swizzled, stride 64 shorts: row r octet o at r*64 + (o ^ (r&7))*8
  __shared__ __attribute__((aligned(16))) short sK[2][64 * 64];    // [j][d] dbuf
  __shared__ __attribute__((aligned(16))) short sVt[64 * 64];      // [d][j] single
  __shared__ __attribute__((aligned(16))) short sP[4][16 * 72];    // per wave [q16][j64]

  auto stageK = [&](int kt, int d) {
#pragma unroll
    for (int i = 0; i < 2; i++) {
      int c = i * 256 + tid;
      int r = c >> 3, cc = c & 7;
      gll16(&QKV[((long)(b * 2048 + kt * 64 + r)) * 1536 + 1024 + kvh * 64 + ((cc ^ (r & 7)) * 8)],
            &sK[d][(i * 256 + w * 64) * 8]);
    }
  };
  auto stageV = [&](int kt) {
#pragma unroll
    for (int i = 0; i < 2; i++) {
      int c = i * 256 + tid;
      int r = c >> 3, cc = c & 7;
      gll16(&Vt[((long)(bkv * 64 + r)) * 2048 + kt * 64 + ((cc ^ (r & 7)) * 8)],
            &sVt[(i * 256 + w * 64) * 8]);
    }
  };

  stageK(0, 0);                       // 2 gll16/thread in flight

  // Q fragments (B-operand: lane c16 = q, octet over d), from global once
  bf16x8 qf[2];
  {
    long tok = (long)b * 2048 + q0 + c16;
#pragma unroll
    for (int ks = 0; ks < 2; ks++)
      qf[ks] = *(const bf16x8*)(&QKV[tok * 1536 + h * 64 + ks * 32 + qd * 8]);
  }

  f32x4 Ot[4] = {};                 // O^T: row=d, col=q=c16 (un-normalized)
  float l_i = 0.f;                  // per-lane partial sum

  const int ntiles = (qt >> 2) + 1;
  for (int kt = 0; kt < ntiles; kt++) {
    const int cur = kt & 1;
    asm volatile("" ::: "memory");
    __builtin_amdgcn_s_barrier();             // prev compute done: sVt & sK[cur^1] free
    stageV(kt);                               // 2 gll (waited before PV)
    if (kt + 1 < ntiles) {
      stageK(kt + 1, cur ^ 1);                // 2 gll
      asm volatile("s_waitcnt vmcnt(4)" ::: "memory");  // prior K staging retired
    } else {
      asm volatile("s_waitcnt vmcnt(2)" ::: "memory");
    }
    __builtin_amdgcn_s_barrier();             // sK[cur] visible to all waves
    asm volatile("" ::: "memory");

    // ---- S^T = K Q^T : A = K (c16 = j), B = Q (c16 = q) ----
    f32x4 St[4];
#pragma unroll
    for (int jc = 0; jc < 4; jc++) {
      int rr = jc * 16 + c16;
      bf16x8 kf0 = *(const bf16x8*)(&sK[cur][rr * 64 + ((0 + qd) ^ (rr & 7)) * 8]);
      bf16x8 kf1 = *(const bf16x8*)(&sK[cur][rr * 64 + ((4 + qd) ^ (rr & 7)) * 8]);
      f32x4 z = {};
      z = __builtin_amdgcn_mfma_f32_16x16x32_bf16(kf0, qf[0], z, 0, 0, 0);
      z = __builtin_amdgcn_mfma_f32_16x16x32_bf16(kf1, qf[1], z, 0, 0, 0);
      St[jc] = z;
    }

    // ---- causal mask on the diagonal (last) tile only ----
    if (kt == ntiles - 1) {
      int qg = q0 + c16 - kt * 64;            // q relative to tile
#pragma unroll
      for (int jc = 0; jc < 4; jc++)
#pragma unroll
        for (int r = 0; r < 4; r++)
          if (jc * 16 + qd * 4 + r > qg) St[jc][r] = -3e38f;
    }

    // ---- static-max softmax: p = exp2(CSOFT*s - CMAX); per-lane only ----
    {
      float rs = 0.f;
#pragma unroll
      for (int jc = 0; jc < 4; jc++) {
        unsigned u[4];
#pragma unroll
        for (int r = 0; r < 4; r++) {
          float p = exp2f(fmaf(CSOFT, St[jc][r], -CMAX));
          u[r] = __builtin_bit_cast(unsigned, p) & 0xffff0000u;   // truncate to bf16
          rs += __builtin_bit_cast(float, u[r]);                  // l from truncated p
        }
        int2 pk;
        pk.x = (int)((u[0] >> 16) | u[1]);
        pk.y = (int)((u[2] >> 16) | u[3]);
        *(int2*)(&sP[w][c16 * 72 + jc * 16 + qd * 4]) = pk;
      }
      l_i += rs;
    }
    asm volatile("s_waitcnt lgkmcnt(0)" ::: "memory");  // own sP writes retired

    // V tile arrived? (own gll) then barrier so ALL waves' chunks are in
    if (kt + 1 < ntiles) asm volatile("s_waitcnt vmcnt(2)" ::: "memory");
    else                 asm volatile("s_waitcnt vmcnt(0)" ::: "memory");
    __builtin_amdgcn_s_barrier();
    asm volatile("" ::: "memory");

    // ---- O^T += V^T P^T : A = Vt (c16 = d), B = P^T (c16 = q) ----
#pragma unroll
    for (int ks2 = 0; ks2 < 2; ks2++) {
      bf16x8 pf = *(const bf16x8*)(&sP[w][c16 * 72 + ks2 * 32 + qd * 8]);
#pragma unroll
      for (int dt = 0; dt < 4; dt++) {
        int rr = dt * 16 + c16;
        bf16x8 vf = *(const bf16x8*)(&sVt[rr * 64 + (((ks2 * 4 + qd) ^ (rr & 7)) * 8)]);
        Ot[dt] = __builtin_amdgcn_mfma_f32_16x16x32_bf16(vf, pf, Ot[dt], 0, 0, 0);
      }
    }
  }

  // ---- epilogue: reduce l across the 4 qd groups, normalize, store O^T ----
  {
    float l = l_i;
    l += __shfl_xor(l, 16, 64);
    l += __shfl_xor(l, 32, 64);
    float inv = 1.f / l;
    long tok = (long)b * 2048 + q0 + c16;
#pragma unroll
    for (int dt = 0; dt < 4; dt++) {
      short4 o;
      o.x = f2bf(Ot[dt][0] * inv);
      o.y = f2bf(Ot[dt][1] * inv);
      o.z = f2bf(Ot[dt][2] * inv);
      o.w = f2bf(Ot[dt][3] * inv);
      *(short4*)(&Aout[tok * 1024 + h * 64 + dt * 16 + qd * 4]) = o;
    }
  }
}

// ---------- launch ----------
extern "C" void kernel_launch(void* const* d_in, const int* in_sizes, int n_in,
                              void* d_out, int out_size, void* d_ws, size_t ws_size,
                              hipStream_t stream) {
  const float* x   = (const float*)d_in[0];   // [2,2048,1024]
  const float* Wq  = (const float*)d_in[1];   // [1024,1024]
  const float* Wkv = (const float*)d_in[2];   // [1024,512]
  const float* Wo  = (const float*)d_in[3];   // [1024,1024]

  char* ws = (char*)d_ws;
  short* xb    = (short*)(ws);                          //  8,388,608 B
  short* Wqkvt = (short*)(ws + 8388608);                //  3,145,728 B  [1536][1024]
  short* Wot   = (short*)(ws + 11534336);               //  2,097,152 B  [1024][1024]
  short* QKV   = (short*)(ws + 13631488);               // 12,582,912 B  [4096][1536]
  short* attn  = (short*)(ws + 26214400);               //  8,388,608 B  [4096][1024]
  short* Vtb   = (short*)d_out;                         //  4,194,304 B scratch in d_out
                                                        //  (gemm2 overwrites ALL of d_out)

  // preprocessing: x->bf16 + weight transposes, one launch
  fused_pre<<<dim3(6656), 256, 0, stream>>>(x, Wq, Wkv, Wo, xb, Wqkvt, Wot);

  // QKV = xb @ Wqkv  (M=4096,N=1536,K=1024): 64x96 tiles, grid 1024 = 4/CU
  gemm_bt<3, true, true><<<dim3(16, 64), 256, 0, stream>>>(xb, Wqkvt, QKV, Vtb, 1536, 1024);

  // attention: 1024 blocks = 4/CU fully resident, balanced qt order
  attn_kernel<<<dim3(1024), 256, 0, stream>>>(QKV, Vtb, attn);

  // out = attn @ Wo  (M=4096,N=1024,K=1024): 64x64 tiles, grid 1024 = 4/CU
  gemm_bt<2, false, false><<<dim3(16, 64), 256, 0, stream>>>(attn, Wot, d_out, nullptr, 1024, 1024);
}